// Round 2
// baseline (12264.143 us; speedup 1.0000x reference)
//
#include <hip/hip_runtime.h>

typedef unsigned int uint32;
typedef unsigned short ushort16;

// Problem dims (fixed by the reference setup_inputs)
#define Bb   512
#define QL   128
#define AL   512
#define Ee   300
#define Ff   400
#define KK   3
#define PP   (Ee*KK)   // 900

static __device__ __forceinline__ float bf_lo(uint32 u) { return __uint_as_float(u << 16); }
static __device__ __forceinline__ float bf_hi(uint32 u) { return __uint_as_float(u & 0xffff0000u); }
static __device__ __forceinline__ float bf1(ushort16 u) { return __uint_as_float(((uint32)u) << 16); }
static __device__ __forceinline__ ushort16 f2bf(float f) {
    uint32 u = __float_as_uint(f);
    uint32 r = (u + 0x7fffu + ((u >> 16) & 1u)) >> 16;   // RNE
    return (ushort16)r;
}

// ---------------------------------------------------------------------------
// prep: Wt[p][f] = W[f][p] (p = e*3+k), Wp[p][g] = sum_f U[f][g]*W[f][p],
//       bp[g] = sum_f U[f][g]*cb[f]
// ---------------------------------------------------------------------------
__global__ __launch_bounds__(256) void prep_kernel(
        const float* __restrict__ W, const float* __restrict__ cb,
        const float* __restrict__ U,
        float* __restrict__ Wt, float* __restrict__ Wp, float* __restrict__ bp)
{
    int p = blockIdx.x;
    int t = threadIdx.x;
    if (p < PP) {
        __shared__ float wcol[Ff];
        for (int f = t; f < Ff; f += 256) wcol[f] = W[(size_t)f * PP + p];
        __syncthreads();
        for (int f = t; f < Ff; f += 256) Wt[p * Ff + f] = wcol[f];
        for (int g = t; g < Ff; g += 256) {
            float s = 0.f;
            for (int f = 0; f < Ff; ++f) s += wcol[f] * U[f * Ff + g];
            Wp[p * Ff + g] = s;
        }
    } else {
        for (int g = t; g < Ff; g += 256) {
            float s = 0.f;
            for (int f = 0; f < Ff; ++f) s += cb[f] * U[f * Ff + g];
            bp[g] = s;
        }
    }
}

// ---------------------------------------------------------------------------
// conv: out[b][l][f] = bias[f] + sum_{e,k} emb[tok[b][l-1+k]][e] * Wt[e*3+k][f]
// grid (nb, L/64), block 256. lanes = l (64), wave id = f-group.
// toks is already offset to the chunk's first batch; out is chunk-local.
// ---------------------------------------------------------------------------
__global__ __launch_bounds__(256) void conv_kernel(
        const int* __restrict__ toks, int L,
        const float* __restrict__ emb,
        const float* __restrict__ wt,    // [900][400]
        const float* __restrict__ bias,  // [400]
        ushort16* __restrict__ out)      // [nb][L][400] bf16
{
    __shared__ ushort16 xs[66][302];
    __shared__ int tokid[66];
    const int t = threadIdx.x;
    const int b = blockIdx.x;
    const int l0 = blockIdx.y * 64;

    if (t < 66) {
        int gl = l0 - 1 + t;
        tokid[t] = (gl >= 0 && gl < L) ? toks[(size_t)b * L + gl] : 0;
    }
    __syncthreads();
    for (int i = t; i < 66 * Ee; i += 256) {
        int r = i / Ee;
        int c = i - r * Ee;
        xs[r][c] = f2bf(emb[(size_t)tokid[r] * Ee + c]);
    }
    __syncthreads();

    const int l  = t & 63;
    int fg = (t >> 6) * 10;
    fg = __builtin_amdgcn_readfirstlane(fg);   // wave-uniform -> force SGPR
    ushort16* orow = out + ((size_t)b * L + l0 + l) * Ff;

    for (int fp = 0; fp < 10; ++fp) {
        const int f0 = __builtin_amdgcn_readfirstlane(fp * 40 + fg);
        float acc[10];
#pragma unroll
        for (int i = 0; i < 10; ++i) acc[i] = bias[f0 + i];

        for (int e = 0; e < Ee; e += 2) {
            uint32 x0 = *(const uint32*)&xs[l][e];
            uint32 x1 = *(const uint32*)&xs[l + 1][e];
            uint32 x2 = *(const uint32*)&xs[l + 2][e];
            float x0a = bf_lo(x0), x0b = bf_hi(x0);
            float x1a = bf_lo(x1), x1b = bf_hi(x1);
            float x2a = bf_lo(x2), x2b = bf_hi(x2);
            const float* wb = wt + (size_t)(e * 3) * Ff + f0;  // uniform -> s_load
#pragma unroll
            for (int i = 0; i < 10; ++i) {
                acc[i] += wb[i]          * x0a + wb[400 + i]  * x1a + wb[800 + i]  * x2a
                        + wb[1200 + i]   * x0b + wb[1600 + i] * x1b + wb[2000 + i] * x2b;
            }
        }
#pragma unroll
        for (int i = 0; i < 5; ++i) {
            uint32 p = (uint32)f2bf(acc[2 * i]) | ((uint32)f2bf(acc[2 * i + 1]) << 16);
            *(uint32*)&orow[f0 + 2 * i] = p;
        }
    }
}

// ---------------------------------------------------------------------------
// fused: per-batch block. Gpre = Q'^T A (pre-tanh), row/col max, tanh+softmax,
// rQ/rA pooling, cosine. Never materializes G.
// ---------------------------------------------------------------------------
static __device__ __forceinline__ float block_reduce_max(float v, volatile float* red) {
    int t = threadIdx.x;
    red[t] = v; __syncthreads();
    for (int s = 128; s > 0; s >>= 1) {
        if (t < s) red[t] = fmaxf(red[t], red[t + s]);
        __syncthreads();
    }
    float r = red[0]; __syncthreads();
    return r;
}
static __device__ __forceinline__ float block_reduce_sum(float v, volatile float* red) {
    int t = threadIdx.x;
    red[t] = v; __syncthreads();
    for (int s = 128; s > 0; s >>= 1) {
        if (t < s) red[t] = red[t] + red[t + s];
        __syncthreads();
    }
    float r = red[0]; __syncthreads();
    return r;
}

__global__ __launch_bounds__(256) void fused_kernel(
        const ushort16* __restrict__ Q,   // [nb][128][400] bf16
        const ushort16* __restrict__ Qp,  // [nb][128][400] bf16
        const ushort16* __restrict__ A,   // [nb][512][400] bf16
        float* __restrict__ out)          // [nb]
{
    __shared__ __align__(16) ushort16 as_[32][408];  // a-chunk, 16B-aligned rows
    __shared__ float colpart[32][17];
    __shared__ float colv[AL];
    __shared__ float rowp4[QL][5];
    __shared__ float roq[QL];
    __shared__ float red[256];

    const int t  = threadIdx.x;
    const int b  = blockIdx.x;
    const int qg = t & 15;    // q = qg + 16j, j=0..7
    const int ag = t >> 4;    // a_local = ag*2 + {0,1}

    const uint4* qrow[8];
#pragma unroll
    for (int j = 0; j < 8; ++j)
        qrow[j] = (const uint4*)(Qp + ((size_t)b * QL + qg + 16 * j) * Ff);

    float rp[8];
#pragma unroll
    for (int j = 0; j < 8; ++j) rp[j] = -1e30f;

    for (int c = 0; c < AL / 32; ++c) {
        __syncthreads();   // protect as_/colpart reuse
        // stage 32 A rows (bf16, 200 dwords/row) into LDS (row stride 204 dwords)
        const uint32* Asrc = (const uint32*)(A + ((size_t)b * AL + c * 32) * Ff);
        for (int i = t; i < 32 * 200; i += 256) {
            int r  = i / 200;
            int cc = i - r * 200;
            ((uint32*)&as_[r][0])[cc] = Asrc[r * 200 + cc];
        }
        __syncthreads();

        float acc[8][2];
#pragma unroll
        for (int j = 0; j < 8; ++j) { acc[j][0] = 0.f; acc[j][1] = 0.f; }

        const uint4* ar0 = (const uint4*)&as_[ag * 2][0];
        const uint4* ar1 = (const uint4*)&as_[ag * 2 + 1][0];
        for (int i4 = 0; i4 < Ff / 8; ++i4) {
            uint4 av0 = ar0[i4], av1 = ar1[i4];
            float a0[8], a1[8];
            a0[0] = bf_lo(av0.x); a0[1] = bf_hi(av0.x); a0[2] = bf_lo(av0.y); a0[3] = bf_hi(av0.y);
            a0[4] = bf_lo(av0.z); a0[5] = bf_hi(av0.z); a0[6] = bf_lo(av0.w); a0[7] = bf_hi(av0.w);
            a1[0] = bf_lo(av1.x); a1[1] = bf_hi(av1.x); a1[2] = bf_lo(av1.y); a1[3] = bf_hi(av1.y);
            a1[4] = bf_lo(av1.z); a1[5] = bf_hi(av1.z); a1[6] = bf_lo(av1.w); a1[7] = bf_hi(av1.w);
#pragma unroll
            for (int j = 0; j < 8; ++j) {
                uint4 qv = qrow[j][i4];
                float xq[8];
                xq[0] = bf_lo(qv.x); xq[1] = bf_hi(qv.x); xq[2] = bf_lo(qv.y); xq[3] = bf_hi(qv.y);
                xq[4] = bf_lo(qv.z); xq[5] = bf_hi(qv.z); xq[6] = bf_lo(qv.w); xq[7] = bf_hi(qv.w);
#pragma unroll
                for (int e = 0; e < 8; ++e) {
                    acc[j][0] = fmaf(xq[e], a0[e], acc[j][0]);
                    acc[j][1] = fmaf(xq[e], a1[e], acc[j][1]);
                }
            }
        }
        // row partial maxes (persist in regs)
        float cm0 = -1e30f, cm1 = -1e30f;
#pragma unroll
        for (int j = 0; j < 8; ++j) {
            rp[j] = fmaxf(rp[j], fmaxf(acc[j][0], acc[j][1]));
            cm0 = fmaxf(cm0, acc[j][0]);
            cm1 = fmaxf(cm1, acc[j][1]);
        }
        colpart[ag * 2][qg]     = cm0;
        colpart[ag * 2 + 1][qg] = cm1;
        __syncthreads();
        if (t < 32) {
            float m = colpart[t][0];
#pragma unroll
            for (int k = 1; k < 16; ++k) m = fmaxf(m, colpart[t][k]);
            colv[c * 32 + t] = m;
        }
    }

    // row maxes: reduce over ag (16 groups) = xor-16/32 within wave + LDS across waves
#pragma unroll
    for (int j = 0; j < 8; ++j) {
        float v = rp[j];
        v = fmaxf(v, __shfl_xor(v, 16));
        v = fmaxf(v, __shfl_xor(v, 32));
        if ((t & 63) < 16) rowp4[qg + 16 * j][t >> 6] = v;
    }
    __syncthreads();

    // softmax over row maxes (tanh applied only to the 128 maxes)
    float v = -1e30f;
    if (t < QL) {
        float rm = fmaxf(fmaxf(rowp4[t][0], rowp4[t][1]), fmaxf(rowp4[t][2], rowp4[t][3]));
        v = tanhf(rm);
    }
    float vmax = block_reduce_max(v, red);
    float ex = (t < QL) ? __expf(v - vmax) : 0.f;
    float ssum = block_reduce_sum(ex, red);
    if (t < QL) roq[t] = ex / ssum;
    __syncthreads();

    // rQ (each thread owns f = t and f = t+256)
    const int f0v = t, f1v = t + 256;
    float rq0 = 0.f, rq1 = 0.f;
    const ushort16* Qb = Q + (size_t)b * QL * Ff;
    for (int q = 0; q < QL; ++q) {
        float w = roq[q];
        rq0 = fmaf(bf1(Qb[q * Ff + f0v]), w, rq0);
        if (f1v < Ff) rq1 = fmaf(bf1(Qb[q * Ff + f1v]), w, rq1);
    }

    // softmax over col maxes
    float c0 = tanhf(colv[t]);
    float c1 = tanhf(colv[t + 256]);
    float cmax = block_reduce_max(fmaxf(c0, c1), red);
    float e0 = __expf(c0 - cmax), e1 = __expf(c1 - cmax);
    float csum = block_reduce_sum(e0 + e1, red);
    colv[t] = e0 / csum;
    colv[t + 256] = e1 / csum;
    __syncthreads();

    // rA
    float ra0 = 0.f, ra1 = 0.f;
    const ushort16* Ab = A + (size_t)b * AL * Ff;
    for (int a = 0; a < AL; ++a) {
        float w = colv[a];
        ra0 = fmaf(bf1(Ab[a * Ff + f0v]), w, ra0);
        if (f1v < Ff) ra1 = fmaf(bf1(Ab[a * Ff + f1v]), w, ra1);
    }

    // cosine
    float dd = block_reduce_sum(rq0 * ra0 + rq1 * ra1, red);
    float qq = block_reduce_sum(rq0 * rq0 + rq1 * rq1, red);
    float aa = block_reduce_sum(ra0 * ra0 + ra1 * ra1, red);
    if (t == 0) {
        float nq = fmaxf(sqrtf(qq), 1e-8f);
        float na = fmaxf(sqrtf(aa), 1e-8f);
        out[b] = dd / (nq * na);
    }
}

// ---------------------------------------------------------------------------
// launch — batch-chunked so the workspace footprint adapts to ws_size.
// Chunk count is a pure function of ws_size (constant) -> graph-capture safe.
// ---------------------------------------------------------------------------
extern "C" void kernel_launch(void* const* d_in, const int* in_sizes, int n_in,
                              void* d_out, int out_size, void* d_ws, size_t ws_size,
                              hipStream_t stream)
{
    const int*   question = (const int*)d_in[0];
    const int*   answer   = (const int*)d_in[1];
    const float* emb      = (const float*)d_in[2];
    const float* conv_w   = (const float*)d_in[3];
    const float* conv_b   = (const float*)d_in[4];
    const float* U        = (const float*)d_in[5];
    float* out = (float*)d_out;

    char* ws = (char*)d_ws;
    // Fixed region: wt (1.44 MB) + wp (1.44 MB) + bp (1.6 KB)
    const size_t WT_B  = (size_t)PP * Ff * 4;          // 1,440,000
    const size_t BP_B  = (size_t)Ff * 4;               // 1,600
    const size_t FIXED = 2 * WT_B + BP_B;              // 2,881,600
    float* wt = (float*)(ws + 0);
    float* wp = (float*)(ws + WT_B);
    float* bp = (float*)(ws + 2 * WT_B);

    // Per-batch chunk buffers: Q + Qp (QL*Ff bf16 each) + A (AL*Ff bf16)
    const size_t QROW = (size_t)QL * Ff * 2;           // 102,400
    const size_t AROW = (size_t)AL * Ff * 2;           // 409,600
    const size_t PER_B = 2 * QROW + AROW;              // 614,400

    size_t avail = (ws_size > FIXED) ? (ws_size - FIXED) : 0;
    int CB = (int)(avail / PER_B);
    if (CB > Bb) CB = Bb;
    if (CB < 1)  CB = 1;   // last resort; needs ~3.5 MB of ws

    ushort16* Qb = (ushort16*)(ws + FIXED);
    ushort16* Qp = (ushort16*)(ws + FIXED + (size_t)CB * QROW);
    ushort16* Ab = (ushort16*)(ws + FIXED + (size_t)CB * 2 * QROW);

    prep_kernel<<<PP + 1, 256, 0, stream>>>(conv_w, conv_b, U, wt, wp, bp);

    for (int b0 = 0; b0 < Bb; b0 += CB) {
        int nb = (Bb - b0 < CB) ? (Bb - b0) : CB;
        conv_kernel<<<dim3(nb, QL / 64), 256, 0, stream>>>(
            question + (size_t)b0 * QL, QL, emb, wt, conv_b, Qb);
        conv_kernel<<<dim3(nb, AL / 64), 256, 0, stream>>>(
            answer + (size_t)b0 * AL, AL, emb, wt, conv_b, Ab);
        conv_kernel<<<dim3(nb, QL / 64), 256, 0, stream>>>(
            question + (size_t)b0 * QL, QL, emb, wp, bp, Qp);
        fused_kernel<<<nb, 256, 0, stream>>>(Qb, Qp, Ab, out + b0);
    }
}

// Round 3
// 1419.320 us; speedup vs baseline: 8.6409x; 8.6409x over previous
//
#include <hip/hip_runtime.h>
#include <math.h>

typedef unsigned int   uint32;
typedef unsigned short ushort16;
typedef __attribute__((ext_vector_type(8))) short  short8;   // 8 bf16 = 4 VGPRs (MFMA A/B frag)
typedef __attribute__((ext_vector_type(4))) float  floatx4;  // MFMA C/D frag

// Problem dims
#define Bb   512
#define QLn  128
#define ALn  512
#define En   300
#define Fn   400
// Padded dims
#define FP   512      // f padded 400 -> 512 (zero weights/bias beyond 400)
#define EPAD 320      // e padded 300 -> 320 per shift; K_total = 3*320 = 960

static __device__ __forceinline__ float bf_lo(uint32 u) { return __uint_as_float(u << 16); }
static __device__ __forceinline__ float bf_hi(uint32 u) { return __uint_as_float(u & 0xffff0000u); }
static __device__ __forceinline__ ushort16 f2bf(float f) {
    uint32 u = __float_as_uint(f);
    uint32 r = (u + 0x7fffu + ((u >> 16) & 1u)) >> 16;   // RNE
    return (ushort16)r;
}

// ---------------------------------------------------------------------------
// prep2: Wt2[f][p] = W[f][e][kk] (p = kk*320+e) bf16, zero-padded to f<512,e<320
//        Wp2[g][p] = sum_f U[f][g] * W[f][e][kk]
//        bias2[f] = cb[f] (0 for f>=400); bp2[g] = sum_f U[f][g]*cb[f]
// One block per output row g (512 blocks).
// ---------------------------------------------------------------------------
__global__ __launch_bounds__(256) void prep2_kernel(
        const float* __restrict__ W,   // [400][300][3]
        const float* __restrict__ cb,  // [400]
        const float* __restrict__ U,   // [400][400]
        ushort16* __restrict__ Wt2,    // [512][960] bf16
        ushort16* __restrict__ Wp2,    // [512][960] bf16
        float* __restrict__ bias2, float* __restrict__ bp2)
{
    const int g = blockIdx.x;
    const int t = threadIdx.x;
    __shared__ float Ucol[Fn];
    __shared__ float red[256];
    for (int f = t; f < Fn; f += 256) Ucol[f] = (g < Fn) ? U[f * Fn + g] : 0.f;
    __syncthreads();

    for (int p = t; p < 960; p += 256) {
        int kk = p / EPAD, e = p - kk * EPAD;
        float wv = 0.f, wpv = 0.f;
        if (e < En) {
            if (g < Fn) wv = W[(size_t)g * 900 + e * 3 + kk];
            for (int f = 0; f < Fn; ++f) wpv += Ucol[f] * W[(size_t)f * 900 + e * 3 + kk];
        }
        Wt2[(size_t)g * 960 + p] = f2bf(wv);
        Wp2[(size_t)g * 960 + p] = f2bf(wpv);
    }

    float part = 0.f;
    for (int f = t; f < Fn; f += 256) part += Ucol[f] * cb[f];
    red[t] = part; __syncthreads();
    for (int s = 128; s > 0; s >>= 1) { if (t < s) red[t] += red[t + s]; __syncthreads(); }
    if (t == 0) { bp2[g] = red[0]; bias2[g] = (g < Fn) ? cb[g] : 0.f; }
}

// ---------------------------------------------------------------------------
// gather: Eb[b][r][0..320) = bf16(emb[tok(r-1)]) with e>=300 zero.
// Row r=0 / r=L+1 use token 0 whose embedding row is all-zero (padding_idx).
// grid (nb, rows), block 128.
// ---------------------------------------------------------------------------
__global__ __launch_bounds__(128) void gather_kernel(
        const int* __restrict__ toks, int L,
        const float* __restrict__ emb,
        char* __restrict__ Eb, int rowsPerB)
{
    const int b = blockIdx.x, r = blockIdx.y, j = threadIdx.x;
    const int l = r - 1;
    const int tok = (l >= 0 && l < L) ? toks[(size_t)b * L + l] : 0;
    const float* er = emb + (size_t)tok * En;
    uint32* orow = (uint32*)(Eb + ((size_t)b * rowsPerB + r) * 640);
    for (int d = j; d < 160; d += 128) {   // 160 dwords = 320 bf16
        uint32 v = 0;
        if (d < 150) {
            float2 f2v = *(const float2*)(er + 2 * d);
            v = (uint32)f2bf(f2v.x) | ((uint32)f2bf(f2v.y) << 16);
        }
        orow[d] = v;
    }
}

// ---------------------------------------------------------------------------
// conv_mfma: out[b][l][f] = bias2[f] + sum_{kk,e} Eb[b][l+kk][e] * Wt2[f][kk*320+e]
// m97-style 128x128 tile. grid (nb, L/128, 4). block 256 (4 waves, 2x2).
// K-loop: kk=0..2 (row shift), ks=0..9 (32-wide e-chunks of the padded 320).
// LDS tiles: [128 rows][32 bf16], row stride 80 B (2-way bank alias = free).
// ---------------------------------------------------------------------------
__global__ __launch_bounds__(256) void conv_mfma(
        const char* __restrict__ Eb,   // [nb][rowsPerB][320] bf16
        int rowsPerB, int L,
        const char* __restrict__ Wt2,  // [512][960] bf16
        const float* __restrict__ bias2,
        ushort16* __restrict__ outbuf) // [nb][L][512] bf16
{
    __shared__ __align__(16) char As[128 * 80];
    __shared__ __align__(16) char Bs[128 * 80];
    const int t = threadIdx.x, lane = t & 63, w = t >> 6;
    const int b = blockIdx.x, mt = blockIdx.y, z = blockIdx.z;
    const int wr = w >> 1, wc = w & 1;
    const char* EbB = Eb + ((size_t)b * rowsPerB + (size_t)mt * 128) * 640;
    const char* WB  = Wt2 + (size_t)z * 128 * 1920;

    floatx4 acc[4][4];
    const floatx4 z4 = {0.f, 0.f, 0.f, 0.f};
#pragma unroll
    for (int m = 0; m < 4; ++m)
#pragma unroll
        for (int n = 0; n < 4; ++n) acc[m][n] = z4;

    const int sr = t >> 2;            // staging row (i=0); i=1 uses sr+64
    const int sq = (t & 3) * 16;      // 16B chunk within the 64B k-slice
    const int fm = lane & 15, fq = (lane >> 4) * 16;

    for (int kk = 0; kk < 3; ++kk) {
        for (int ks = 0; ks < 10; ++ks) {
            const int tail = kk * 640 + ks * 64 + sq;  // shared col math:
            // Eb addr = (row+kk)*640 + ks*64 + sq  = row*640 + tail
            // W  addr = row*1920 + kk*640 + ks*64 + sq = row*1920 + tail
            __syncthreads();
            *(uint4*)(As + sr * 80 + sq)        = *(const uint4*)(EbB + (size_t)sr * 640 + tail);
            *(uint4*)(As + (sr + 64) * 80 + sq) = *(const uint4*)(EbB + (size_t)(sr + 64) * 640 + tail);
            *(uint4*)(Bs + sr * 80 + sq)        = *(const uint4*)(WB + (size_t)sr * 1920 + tail);
            *(uint4*)(Bs + (sr + 64) * 80 + sq) = *(const uint4*)(WB + (size_t)(sr + 64) * 1920 + tail);
            __syncthreads();

            short8 afrag[4], bfrag[4];
#pragma unroll
            for (int m = 0; m < 4; ++m)
                afrag[m] = *(const short8*)(As + (wr * 64 + m * 16 + fm) * 80 + fq);
#pragma unroll
            for (int n = 0; n < 4; ++n)
                bfrag[n] = *(const short8*)(Bs + (wc * 64 + n * 16 + fm) * 80 + fq);
#pragma unroll
            for (int m = 0; m < 4; ++m)
#pragma unroll
                for (int n = 0; n < 4; ++n)
                    acc[m][n] = __builtin_amdgcn_mfma_f32_16x16x32_bf16(
                        afrag[m], bfrag[n], acc[m][n], 0, 0, 0);
        }
    }

    // epilogue: +bias, bf16, store. C/D layout: col=lane&15, row=(lane>>4)*4+reg
    float bn[4];
#pragma unroll
    for (int n = 0; n < 4; ++n) bn[n] = bias2[z * 128 + wc * 64 + n * 16 + fm];
    ushort16* ob = outbuf + ((size_t)b * L + (size_t)mt * 128) * FP;
#pragma unroll
    for (int m = 0; m < 4; ++m) {
        const int row = wr * 64 + m * 16 + (lane >> 4) * 4;
#pragma unroll
        for (int n = 0; n < 4; ++n) {
            const int col = z * 128 + wc * 64 + n * 16 + fm;
#pragma unroll
            for (int r = 0; r < 4; ++r)
                ob[(size_t)(row + r) * FP + col] = f2bf(acc[m][n][r] + bn[n]);
        }
    }
}

// ---------------------------------------------------------------------------
// fused: per-batch. Gpre = Q' A^T via MFMA in 4 a-chunks of 128 (K=512, zero-
// padded f). Row/col maxes from C-layout; tanh only on the 640 max values.
// Then softmax + vectorized pooling + cosine. G never materialized.
// ---------------------------------------------------------------------------
static __device__ __forceinline__ float block_reduce_max(float v, volatile float* red) {
    int t = threadIdx.x;
    red[t] = v; __syncthreads();
    for (int s = 128; s > 0; s >>= 1) {
        if (t < s) red[t] = fmaxf(red[t], red[t + s]);
        __syncthreads();
    }
    float r = red[0]; __syncthreads();
    return r;
}
static __device__ __forceinline__ float block_reduce_sum(float v, volatile float* red) {
    int t = threadIdx.x;
    red[t] = v; __syncthreads();
    for (int s = 128; s > 0; s >>= 1) {
        if (t < s) red[t] = red[t] + red[t + s];
        __syncthreads();
    }
    float r = red[0]; __syncthreads();
    return r;
}

__global__ __launch_bounds__(256) void fused_mfma(
        const ushort16* __restrict__ Qv,   // [nb][128][512] bf16
        const ushort16* __restrict__ Qp,   // [nb][128][512] bf16
        const ushort16* __restrict__ Av,   // [nb][512][512] bf16
        float* __restrict__ out)           // [nb]
{
    __shared__ __align__(16) char Qs[128 * 80];
    __shared__ __align__(16) char Asl[128 * 80];
    __shared__ float colM[ALn][2];
    __shared__ float rowM2[QLn][2];
    __shared__ float colv[ALn];
    __shared__ float roq[QLn];
    __shared__ float red[256];

    const int t = threadIdx.x, lane = t & 63, w = t >> 6;
    const int b = blockIdx.x;
    const int wr = w >> 1, wc = w & 1;
    const char* Qpb = (const char*)Qp + (size_t)b * 131072;
    const char* Ab  = (const char*)Av + (size_t)b * 524288;

    const int sr = t >> 2;
    const int sq = (t & 3) * 16;
    const int fm = lane & 15, fq = (lane >> 4) * 16;

    float rp[16];
#pragma unroll
    for (int i = 0; i < 16; ++i) rp[i] = -1e30f;
    const floatx4 z4 = {0.f, 0.f, 0.f, 0.f};

    for (int c = 0; c < 4; ++c) {
        floatx4 acc[4][4];
#pragma unroll
        for (int m = 0; m < 4; ++m)
#pragma unroll
            for (int n = 0; n < 4; ++n) acc[m][n] = z4;

        for (int ks = 0; ks < 16; ++ks) {
            const int colb = ks * 64 + sq;
            __syncthreads();
            *(uint4*)(Qs + sr * 80 + sq)         = *(const uint4*)(Qpb + (size_t)sr * 1024 + colb);
            *(uint4*)(Qs + (sr + 64) * 80 + sq)  = *(const uint4*)(Qpb + (size_t)(sr + 64) * 1024 + colb);
            *(uint4*)(Asl + sr * 80 + sq)        = *(const uint4*)(Ab + (size_t)(c * 128 + sr) * 1024 + colb);
            *(uint4*)(Asl + (sr + 64) * 80 + sq) = *(const uint4*)(Ab + (size_t)(c * 128 + sr + 64) * 1024 + colb);
            __syncthreads();

            short8 qa[4], aa_[4];
#pragma unroll
            for (int m = 0; m < 4; ++m)
                qa[m] = *(const short8*)(Qs + (wr * 64 + m * 16 + fm) * 80 + fq);
#pragma unroll
            for (int n = 0; n < 4; ++n)
                aa_[n] = *(const short8*)(Asl + (wc * 64 + n * 16 + fm) * 80 + fq);
#pragma unroll
            for (int m = 0; m < 4; ++m)
#pragma unroll
                for (int n = 0; n < 4; ++n)
                    acc[m][n] = __builtin_amdgcn_mfma_f32_16x16x32_bf16(
                        qa[m], aa_[n], acc[m][n], 0, 0, 0);
        }

        // row maxes (q rows): lane-local max over n-frags, xor-reduce over cols
#pragma unroll
        for (int m = 0; m < 4; ++m)
#pragma unroll
            for (int r = 0; r < 4; ++r) {
                float v = fmaxf(fmaxf(acc[m][0][r], acc[m][1][r]),
                                fmaxf(acc[m][2][r], acc[m][3][r]));
                v = fmaxf(v, __shfl_xor(v, 1));
                v = fmaxf(v, __shfl_xor(v, 2));
                v = fmaxf(v, __shfl_xor(v, 4));
                v = fmaxf(v, __shfl_xor(v, 8));
                rp[m * 4 + r] = fmaxf(rp[m * 4 + r], v);
            }
        // col maxes (a cols): lane-local max over (m,reg), xor-reduce over rows
#pragma unroll
        for (int n = 0; n < 4; ++n) {
            float v = -1e30f;
#pragma unroll
            for (int m = 0; m < 4; ++m)
#pragma unroll
                for (int r = 0; r < 4; ++r) v = fmaxf(v, acc[m][n][r]);
            v = fmaxf(v, __shfl_xor(v, 16));
            v = fmaxf(v, __shfl_xor(v, 32));
            if ((lane >> 4) == 0) colM[c * 128 + wc * 64 + n * 16 + lane][wr] = v;
        }
    }
    if ((lane & 15) == 0) {
#pragma unroll
        for (int m = 0; m < 4; ++m)
#pragma unroll
            for (int r = 0; r < 4; ++r)
                rowM2[wr * 64 + m * 16 + (lane >> 4) * 4 + r][wc] = rp[m * 4 + r];
    }
    __syncthreads();

    // softmax over tanh(row maxes), q < 128
    float v = -1e30f;
    if (t < QLn) v = tanhf(fmaxf(rowM2[t][0], rowM2[t][1]));
    float vmax = block_reduce_max(v, red);
    float ex = (t < QLn) ? __expf(v - vmax) : 0.f;
    float ssum = block_reduce_sum(ex, red);
    if (t < QLn) roq[t] = ex / ssum;

    // softmax over tanh(col maxes), a < 512 (2 per thread)
    float c0 = tanhf(fmaxf(colM[t][0], colM[t][1]));
    float c1 = tanhf(fmaxf(colM[t + 256][0], colM[t + 256][1]));
    float cmax = block_reduce_max(fmaxf(c0, c1), red);
    float e0 = __expf(c0 - cmax), e1 = __expf(c1 - cmax);
    float csum = block_reduce_sum(e0 + e1, red);
    colv[t] = e0 / csum;
    colv[t + 256] = e1 / csum;
    __syncthreads();

    // pooling: thread t owns f = 2t, 2t+1 (coalesced dword loads)
    const uint32* Qb32 = (const uint32*)((const char*)Qv + (size_t)b * 131072);
    float rq0 = 0.f, rq1 = 0.f;
#pragma unroll 4
    for (int q = 0; q < QLn; ++q) {
        float wv = roq[q];
        uint32 u = Qb32[q * 256 + t];
        rq0 = fmaf(bf_lo(u), wv, rq0);
        rq1 = fmaf(bf_hi(u), wv, rq1);
    }
    const uint32* Ab32 = (const uint32*)Ab;
    float ra0 = 0.f, ra1 = 0.f;
#pragma unroll 4
    for (int a = 0; a < ALn; ++a) {
        float wv = colv[a];
        uint32 u = Ab32[a * 256 + t];
        ra0 = fmaf(bf_lo(u), wv, ra0);
        ra1 = fmaf(bf_hi(u), wv, ra1);
    }

    float dd = block_reduce_sum(rq0 * ra0 + rq1 * ra1, red);
    float qq = block_reduce_sum(rq0 * rq0 + rq1 * rq1, red);
    float aam = block_reduce_sum(ra0 * ra0 + ra1 * ra1, red);
    if (t == 0) {
        float nq = fmaxf(sqrtf(qq), 1e-8f);
        float na = fmaxf(sqrtf(aam), 1e-8f);
        out[b] = dd / (nq * na);
    }
}

// ---------------------------------------------------------------------------
// launch — ws_size-adaptive batch chunking (graph-capture safe: chunk count is
// a pure function of ws_size).
// ---------------------------------------------------------------------------
extern "C" void kernel_launch(void* const* d_in, const int* in_sizes, int n_in,
                              void* d_out, int out_size, void* d_ws, size_t ws_size,
                              hipStream_t stream)
{
    const int*   question = (const int*)d_in[0];
    const int*   answer   = (const int*)d_in[1];
    const float* emb      = (const float*)d_in[2];
    const float* conv_w   = (const float*)d_in[3];
    const float* conv_b   = (const float*)d_in[4];
    const float* U        = (const float*)d_in[5];
    float* out = (float*)d_out;
    char* ws = (char*)d_ws;

    const size_t WT2B  = (size_t)FP * 960 * 2;       // 983,040
    const size_t FIXED = 2 * WT2B + 2 * 2048;        // 1,970,176
    const size_t EBQ   = (size_t)(QLn + 2) * 640;    // 83,200
    const size_t EBA   = (size_t)(ALn + 2) * 640;    // 328,960
    const size_t QB    = (size_t)QLn * FP * 2;       // 131,072
    const size_t AB    = (size_t)ALn * FP * 2;       // 524,288
    const size_t PER_B = EBQ + EBA + 2 * QB + AB;    // 1,198,592

    size_t avail = (ws_size > FIXED) ? (ws_size - FIXED) : 0;
    int CB = (int)(avail / PER_B);
    if (CB > Bb) CB = Bb;
    if (CB < 1)  CB = 1;

    char*  wt2   = ws;
    char*  wp2   = ws + WT2B;
    float* bias2 = (float*)(ws + 2 * WT2B);
    float* bp2   = (float*)(ws + 2 * WT2B + 2048);
    char*  ebq   = ws + FIXED;
    char*  eba   = ebq + (size_t)CB * EBQ;
    char*  qb    = eba + (size_t)CB * EBA;
    char*  qpb   = qb  + (size_t)CB * QB;
    char*  ab    = qpb + (size_t)CB * QB;

    prep2_kernel<<<FP, 256, 0, stream>>>(conv_w, conv_b, U,
                                         (ushort16*)wt2, (ushort16*)wp2, bias2, bp2);

    for (int b0 = 0; b0 < Bb; b0 += CB) {
        int nb = (Bb - b0 < CB) ? (Bb - b0) : CB;
        gather_kernel<<<dim3(nb, QLn + 2), 128, 0, stream>>>(
            question + (size_t)b0 * QLn, QLn, emb, ebq, QLn + 2);
        gather_kernel<<<dim3(nb, ALn + 2), 128, 0, stream>>>(
            answer + (size_t)b0 * ALn, ALn, emb, eba, ALn + 2);
        conv_mfma<<<dim3(nb, 1, 4), 256, 0, stream>>>(ebq, QLn + 2, QLn, wt2, bias2, (ushort16*)qb);
        conv_mfma<<<dim3(nb, 1, 4), 256, 0, stream>>>(ebq, QLn + 2, QLn, wp2, bp2,  (ushort16*)qpb);
        conv_mfma<<<dim3(nb, 4, 4), 256, 0, stream>>>(eba, ALn + 2, ALn, wt2, bias2, (ushort16*)ab);
        fused_mfma<<<dim3(nb), 256, 0, stream>>>((const ushort16*)qb, (const ushort16*)qpb,
                                                 (const ushort16*)ab, out + b0);
    }
}

// Round 4
// 1142.749 us; speedup vs baseline: 10.7321x; 1.2420x over previous
//
#include <hip/hip_runtime.h>
#include <math.h>

typedef unsigned int   uint32;
typedef unsigned short ushort16;
typedef __attribute__((ext_vector_type(8))) short  short8;   // 8 bf16 (MFMA A/B frag)
typedef __attribute__((ext_vector_type(4))) float  floatx4;  // MFMA C/D frag

// Problem dims
#define Bb   512
#define QLn  128
#define ALn  512
#define En   300
#define Fn   400
#define FP   512      // f padded 400 -> 512 (zero weights/bias beyond 400)
#define EPAD 320      // e padded 300 -> 320 per shift; K_total = 3*320 = 960

typedef const __attribute__((address_space(1))) unsigned int guint_t;
typedef __attribute__((address_space(3))) unsigned int luint_t;
// async global->LDS DMA, 16B/lane; LDS dest = wave-uniform base + lane*16
#define GLDS16(g, l) __builtin_amdgcn_global_load_lds((guint_t*)(g), (luint_t*)(l), 16, 0, 0)

static __device__ __forceinline__ float bf_lo(uint32 u) { return __uint_as_float(u << 16); }
static __device__ __forceinline__ float bf_hi(uint32 u) { return __uint_as_float(u & 0xffff0000u); }
static __device__ __forceinline__ ushort16 f2bf(float f) {
    uint32 u = __float_as_uint(f);
    uint32 r = (u + 0x7fffu + ((u >> 16) & 1u)) >> 16;   // RNE
    return (ushort16)r;
}

// ---------------------------------------------------------------------------
// prep2: Wt2[f][p] = W[f][e][kk] (p = kk*320+e) bf16, zero-padded f<512,e<320
//        Wp2[g][p] = sum_f U[f][g]*W[f][e][kk];  bias2[f]=cb[f]; bp2[g]=U^T cb
// ---------------------------------------------------------------------------
__global__ __launch_bounds__(256) void prep2_kernel(
        const float* __restrict__ W,   // [400][300][3]
        const float* __restrict__ cb,  // [400]
        const float* __restrict__ U,   // [400][400]
        ushort16* __restrict__ Wt2,    // [512][960] bf16
        ushort16* __restrict__ Wp2,    // [512][960] bf16
        float* __restrict__ bias2, float* __restrict__ bp2)
{
    const int g = blockIdx.x;
    const int t = threadIdx.x;
    __shared__ float Ucol[Fn];
    __shared__ float red[256];
    for (int f = t; f < Fn; f += 256) Ucol[f] = (g < Fn) ? U[f * Fn + g] : 0.f;
    __syncthreads();

    for (int p = t; p < 960; p += 256) {
        int kk = p / EPAD, e = p - kk * EPAD;
        float wv = 0.f, wpv = 0.f;
        if (e < En) {
            if (g < Fn) wv = W[(size_t)g * 900 + e * 3 + kk];
            for (int f = 0; f < Fn; ++f) wpv += Ucol[f] * W[(size_t)f * 900 + e * 3 + kk];
        }
        Wt2[(size_t)g * 960 + p] = f2bf(wv);
        Wp2[(size_t)g * 960 + p] = f2bf(wpv);
    }

    float part = 0.f;
    for (int f = t; f < Fn; f += 256) part += Ucol[f] * cb[f];
    red[t] = part; __syncthreads();
    for (int s = 128; s > 0; s >>= 1) { if (t < s) red[t] += red[t + s]; __syncthreads(); }
    if (t == 0) { bp2[g] = red[0]; bias2[g] = (g < Fn) ? cb[g] : 0.f; }
}

// ---------------------------------------------------------------------------
// gather: Eb[b][r][0..320) = bf16(emb[tok(r-1)]); r=0 / r=L+1 -> token 0 (zero)
// ---------------------------------------------------------------------------
__global__ __launch_bounds__(128) void gather_kernel(
        const int* __restrict__ toks, int L,
        const float* __restrict__ emb,
        char* __restrict__ Eb, int rowsPerB)
{
    const int b = blockIdx.x, r = blockIdx.y, j = threadIdx.x;
    const int l = r - 1;
    const int tok = (l >= 0 && l < L) ? toks[(size_t)b * L + l] : 0;
    const float* er = emb + (size_t)tok * En;
    uint32* orow = (uint32*)(Eb + ((size_t)b * rowsPerB + r) * 640);
    for (int d = j; d < 160; d += 128) {
        uint32 v = 0;
        if (d < 150) {
            float2 f2v = *(const float2*)(er + 2 * d);
            v = (uint32)f2bf(f2v.x) | ((uint32)f2bf(f2v.y) << 16);
        }
        orow[d] = v;
    }
}

// ---------------------------------------------------------------------------
// conv tile body: 128x128 tile, K=960 (3 shifts x 10 chunks of 32).
// Staging via global_load_lds(16B); LDS stride 64B; XOR swizzle done by
// permuting the GLOBAL source chunk per lane: LDS slot (r, s) holds global
// chunk cg with s = (cg + (r>>1)) & 3 -> fragment-read banks spread 2-way.
// ---------------------------------------------------------------------------
static __device__ __forceinline__ void conv_tile(
        const char* __restrict__ EbB,   // 128-row tile base, row stride 640
        const char* __restrict__ WB,    // weight z-slice, row stride 1920
        const float* __restrict__ biasv, int col0,
        ushort16* __restrict__ ob,      // out row base, row stride FP
        char* As, char* Bs)
{
    const int t = threadIdx.x, lane = t & 63, w = t >> 6;
    const int wr = w >> 1, wc = w & 1;
    const int fm = lane & 15;
    const int cg = ((lane & 3) - ((lane >> 3) & 3)) & 3;
    const int srow = w * 16 + (lane >> 2);
    const char* srcA = EbB + (size_t)srow * 640 + cg * 16;
    const char* srcB = WB  + (size_t)srow * 1920 + cg * 16;
    char* AsW = As + w * 1024;
    char* BsW = Bs + w * 1024;
    const int chunkOff = (((lane >> 4) + (fm >> 1)) & 3) * 16;

    floatx4 acc[4][4];
    const floatx4 zz = {0.f, 0.f, 0.f, 0.f};
#pragma unroll
    for (int m = 0; m < 4; ++m)
#pragma unroll
        for (int n = 0; n < 4; ++n) acc[m][n] = zz;

    for (int kk = 0; kk < 3; ++kk) {
        for (int ks = 0; ks < 10; ++ks) {
            const int tail = kk * 640 + ks * 64;
            __syncthreads();
            GLDS16(srcA + tail,          AsW);
            GLDS16(srcA + 40960 + tail,  AsW + 4096);   // rows 64..127 (64*640)
            GLDS16(srcB + tail,          BsW);
            GLDS16(srcB + 122880 + tail, BsW + 4096);   // rows 64..127 (64*1920)
            __syncthreads();

            short8 af[4], bf[4];
#pragma unroll
            for (int m = 0; m < 4; ++m)
                af[m] = *(const short8*)(As + (wr * 64 + m * 16 + fm) * 64 + chunkOff);
#pragma unroll
            for (int n = 0; n < 4; ++n)
                bf[n] = *(const short8*)(Bs + (wc * 64 + n * 16 + fm) * 64 + chunkOff);
#pragma unroll
            for (int m = 0; m < 4; ++m)
#pragma unroll
                for (int n = 0; n < 4; ++n)
                    acc[m][n] = __builtin_amdgcn_mfma_f32_16x16x32_bf16(
                        af[m], bf[n], acc[m][n], 0, 0, 0);
        }
    }

    float bn[4];
#pragma unroll
    for (int n = 0; n < 4; ++n) bn[n] = biasv[col0 + wc * 64 + n * 16 + fm];
#pragma unroll
    for (int m = 0; m < 4; ++m) {
        const int row = wr * 64 + m * 16 + ((lane >> 4) * 4);
#pragma unroll
        for (int n = 0; n < 4; ++n) {
            const int col = col0 + wc * 64 + n * 16 + fm;
#pragma unroll
            for (int r = 0; r < 4; ++r)
                ob[(size_t)(row + r) * FP + col] = f2bf(acc[m][n][r] + bn[n]);
        }
    }
}

// A-conv: tiles T = b*4+mt, NZ=4 z-variants; block idx = (g*4+z)*8+xcd so all
// z of a tile share an XCD (L2 reuse of the Eb tile).
__global__ __launch_bounds__(256) void conva_mfma(
        const char* __restrict__ Eb, const char* __restrict__ Wt2,
        const float* __restrict__ bias2, ushort16* __restrict__ outbuf, int nTiles)
{
    __shared__ __align__(16) char As[8192];
    __shared__ __align__(16) char Bs[8192];
    const int bx = blockIdx.x;
    const int xcd = bx & 7, rest = bx >> 3;
    const int z = rest & 3, g = rest >> 2;
    const int T = g * 8 + xcd;
    if (T >= nTiles) return;
    const int b = T >> 2, mt = T & 3;
    conv_tile(Eb + ((size_t)b * 514 + (size_t)mt * 128) * 640,
              Wt2 + (size_t)z * 245760,
              bias2, z * 128,
              outbuf + ((size_t)b * ALn + (size_t)mt * 128) * FP,
              As, Bs);
}

// merged Q-convs: tiles T = b, NZ=8 (z<4 -> Wt2->qb, z>=4 -> Wp2->qpb);
// all 8 z share one Eb read per XCD.
__global__ __launch_bounds__(256) void convq_mfma(
        const char* __restrict__ Eb,
        const char* __restrict__ Wt2, const char* __restrict__ Wp2,
        const float* __restrict__ bias2, const float* __restrict__ bp2,
        ushort16* __restrict__ qb, ushort16* __restrict__ qpb, int nb)
{
    __shared__ __align__(16) char As[8192];
    __shared__ __align__(16) char Bs[8192];
    const int bx = blockIdx.x;
    const int xcd = bx & 7, rest = bx >> 3;
    const int z8 = rest & 7, g = rest >> 3;
    const int T = g * 8 + xcd;
    if (T >= nb) return;
    const int zf = z8 & 3;
    const char*  Wsel = (z8 < 4) ? Wt2 : Wp2;
    const float* bsel = (z8 < 4) ? bias2 : bp2;
    ushort16*    osel = (z8 < 4) ? qb : qpb;
    conv_tile(Eb + (size_t)T * 83200,            // 130*640
              Wsel + (size_t)zf * 245760,
              bsel, zf * 128,
              osel + (size_t)T * QLn * FP,
              As, Bs);
}

// ---------------------------------------------------------------------------
// fused_g: block (b, a-chunk c). Gpre = Q' A^T (K=416: cols 400..416 are exact
// zeros). Emits per-chunk row maxes [nb][4][128] and col maxes [nb][512].
// ---------------------------------------------------------------------------
__global__ __launch_bounds__(256) void fused_g(
        const ushort16* __restrict__ Qp,   // [nb][128][512]
        const ushort16* __restrict__ Av,   // [nb][512][512]
        float* __restrict__ rowPart,       // [nb][4][128]
        float* __restrict__ colMg,         // [nb][512]
        int nb)
{
    __shared__ __align__(16) char Qs[8192];
    __shared__ __align__(16) char Asl[8192];
    __shared__ float rowM2[128][2];
    __shared__ float colM2[128][2];

    const int t = threadIdx.x, lane = t & 63, w = t >> 6;
    const int bx = blockIdx.x;
    const int xcd = bx & 7, rest = bx >> 3;
    const int c = rest & 3, g = rest >> 2;
    const int T = g * 8 + xcd;
    if (T >= nb) return;
    const int b = T;
    const int wr = w >> 1, wc = w & 1;
    const int fm = lane & 15;
    const int cg = ((lane & 3) - ((lane >> 3) & 3)) & 3;
    const int srow = w * 16 + (lane >> 2);
    const int chunkOff = (((lane >> 4) + (fm >> 1)) & 3) * 16;

    const char* Qpb = (const char*)Qp + (size_t)b * 131072;
    const char* Ab  = (const char*)Av + (size_t)b * 524288 + (size_t)c * 131072;
    const char* srcQ = Qpb + (size_t)srow * 1024 + cg * 16;
    const char* srcA = Ab  + (size_t)srow * 1024 + cg * 16;
    char* QsW = Qs + w * 1024;
    char* AsW = Asl + w * 1024;

    floatx4 acc[4][4];
    const floatx4 zz = {0.f, 0.f, 0.f, 0.f};
#pragma unroll
    for (int m = 0; m < 4; ++m)
#pragma unroll
        for (int n = 0; n < 4; ++n) acc[m][n] = zz;

    for (int ks = 0; ks < 13; ++ks) {
        const int colb = ks * 64;
        __syncthreads();
        GLDS16(srcQ + colb,         QsW);
        GLDS16(srcQ + 65536 + colb, QsW + 4096);
        GLDS16(srcA + colb,         AsW);
        GLDS16(srcA + 65536 + colb, AsW + 4096);
        __syncthreads();

        short8 qa[4], aa_[4];
#pragma unroll
        for (int m = 0; m < 4; ++m)
            qa[m] = *(const short8*)(Qs + (wr * 64 + m * 16 + fm) * 64 + chunkOff);
#pragma unroll
        for (int n = 0; n < 4; ++n)
            aa_[n] = *(const short8*)(Asl + (wc * 64 + n * 16 + fm) * 64 + chunkOff);
#pragma unroll
        for (int m = 0; m < 4; ++m)
#pragma unroll
            for (int n = 0; n < 4; ++n)
                acc[m][n] = __builtin_amdgcn_mfma_f32_16x16x32_bf16(
                    qa[m], aa_[n], acc[m][n], 0, 0, 0);
    }

    // row maxes (q rows): max over n-frags, xor-reduce over fm (cols)
#pragma unroll
    for (int m = 0; m < 4; ++m)
#pragma unroll
        for (int r = 0; r < 4; ++r) {
            float v = fmaxf(fmaxf(acc[m][0][r], acc[m][1][r]),
                            fmaxf(acc[m][2][r], acc[m][3][r]));
            v = fmaxf(v, __shfl_xor(v, 1));
            v = fmaxf(v, __shfl_xor(v, 2));
            v = fmaxf(v, __shfl_xor(v, 4));
            v = fmaxf(v, __shfl_xor(v, 8));
            if (fm == 0) rowM2[wr * 64 + m * 16 + (lane >> 4) * 4 + r][wc] = v;
        }
    // col maxes: max over (m, reg), xor-reduce over row quads
#pragma unroll
    for (int n = 0; n < 4; ++n) {
        float v = -1e30f;
#pragma unroll
        for (int m = 0; m < 4; ++m)
#pragma unroll
            for (int r = 0; r < 4; ++r) v = fmaxf(v, acc[m][n][r]);
        v = fmaxf(v, __shfl_xor(v, 16));
        v = fmaxf(v, __shfl_xor(v, 32));
        if (lane < 16) colM2[wc * 64 + n * 16 + lane][wr] = v;
    }
    __syncthreads();
    if (t < 128) {
        rowPart[((size_t)b * 4 + c) * 128 + t] = fmaxf(rowM2[t][0], rowM2[t][1]);
        colMg[(size_t)b * 512 + c * 128 + t]   = fmaxf(colM2[t][0], colM2[t][1]);
    }
}

// ---------------------------------------------------------------------------
// fused_pool: per-batch softmax over tanh(maxes) + pooling + cosine.
// ---------------------------------------------------------------------------
static __device__ __forceinline__ float block_reduce_max(float v, volatile float* red) {
    int t = threadIdx.x;
    red[t] = v; __syncthreads();
    for (int s = 128; s > 0; s >>= 1) {
        if (t < s) red[t] = fmaxf(red[t], red[t + s]);
        __syncthreads();
    }
    float r = red[0]; __syncthreads();
    return r;
}
static __device__ __forceinline__ float block_reduce_sum(float v, volatile float* red) {
    int t = threadIdx.x;
    red[t] = v; __syncthreads();
    for (int s = 128; s > 0; s >>= 1) {
        if (t < s) red[t] = red[t] + red[t + s];
        __syncthreads();
    }
    float r = red[0]; __syncthreads();
    return r;
}

__global__ __launch_bounds__(256) void fused_pool(
        const ushort16* __restrict__ Qv,   // [nb][128][512]
        const ushort16* __restrict__ Av,   // [nb][512][512]
        const float* __restrict__ rowPart, // [nb][4][128]
        const float* __restrict__ colMg,   // [nb][512]
        float* __restrict__ out)
{
    __shared__ float colv[ALn];
    __shared__ float roq[QLn];
    __shared__ float red[256];
    const int t = threadIdx.x, b = blockIdx.x;

    float v = -1e30f;
    if (t < QLn) {
        const float* rp = rowPart + (size_t)b * 512;
        float rm = fmaxf(fmaxf(rp[t], rp[128 + t]), fmaxf(rp[256 + t], rp[384 + t]));
        v = tanhf(rm);
    }
    float vmax = block_reduce_max(v, red);
    float ex = (t < QLn) ? __expf(v - vmax) : 0.f;
    float ssum = block_reduce_sum(ex, red);
    if (t < QLn) roq[t] = ex / ssum;

    float c0 = tanhf(colMg[(size_t)b * 512 + t]);
    float c1 = tanhf(colMg[(size_t)b * 512 + 256 + t]);
    float cmax = block_reduce_max(fmaxf(c0, c1), red);
    float e0 = __expf(c0 - cmax), e1 = __expf(c1 - cmax);
    float csum = block_reduce_sum(e0 + e1, red);
    colv[t] = e0 / csum;
    colv[t + 256] = e1 / csum;
    __syncthreads();

    const uint32* Qb32 = (const uint32*)((const char*)Qv + (size_t)b * 131072);
    float rq0 = 0.f, rq1 = 0.f;
#pragma unroll 4
    for (int q = 0; q < QLn; ++q) {
        float wv = roq[q];
        uint32 u = Qb32[q * 256 + t];
        rq0 = fmaf(bf_lo(u), wv, rq0);
        rq1 = fmaf(bf_hi(u), wv, rq1);
    }
    const uint32* Ab32 = (const uint32*)((const char*)Av + (size_t)b * 524288);
    float ra0 = 0.f, ra1 = 0.f;
#pragma unroll 4
    for (int a = 0; a < ALn; ++a) {
        float wv = colv[a];
        uint32 u = Ab32[a * 256 + t];
        ra0 = fmaf(bf_lo(u), wv, ra0);
        ra1 = fmaf(bf_hi(u), wv, ra1);
    }

    float dd  = block_reduce_sum(rq0 * ra0 + rq1 * ra1, red);
    float qq  = block_reduce_sum(rq0 * rq0 + rq1 * rq1, red);
    float aam = block_reduce_sum(ra0 * ra0 + ra1 * ra1, red);
    if (t == 0) {
        float nq = fmaxf(sqrtf(qq), 1e-8f);
        float na = fmaxf(sqrtf(aam), 1e-8f);
        out[b] = dd / (nq * na);
    }
}

// ---------------------------------------------------------------------------
// launch — ws_size-adaptive batch chunking (pure function of ws_size).
// ---------------------------------------------------------------------------
extern "C" void kernel_launch(void* const* d_in, const int* in_sizes, int n_in,
                              void* d_out, int out_size, void* d_ws, size_t ws_size,
                              hipStream_t stream)
{
    const int*   question = (const int*)d_in[0];
    const int*   answer   = (const int*)d_in[1];
    const float* emb      = (const float*)d_in[2];
    const float* conv_w   = (const float*)d_in[3];
    const float* conv_b   = (const float*)d_in[4];
    const float* U        = (const float*)d_in[5];
    float* out = (float*)d_out;
    char* ws = (char*)d_ws;

    const size_t WT2B  = (size_t)FP * 960 * 2;       // 983,040
    const size_t FIXED = 2 * WT2B + 2 * 2048;        // 1,970,176
    const size_t EBQ   = 130 * 640;                  // 83,200
    const size_t EBA   = 514 * 640;                  // 328,960
    const size_t QB    = (size_t)QLn * FP * 2;       // 131,072
    const size_t AB    = (size_t)ALn * FP * 2;       // 524,288
    const size_t MXB   = 4096;                       // rowPart + colMg
    const size_t PER_B = EBQ + EBA + 2 * QB + AB + MXB;  // 1,202,688

    size_t avail = (ws_size > FIXED) ? (ws_size - FIXED) : 0;
    int CB = (int)(avail / PER_B);
    if (CB > Bb) CB = Bb;
    if (CB < 1)  CB = 1;

    char*  wt2   = ws;
    char*  wp2   = ws + WT2B;
    float* bias2 = (float*)(ws + 2 * WT2B);
    float* bp2   = (float*)(ws + 2 * WT2B + 2048);
    char*  ebq   = ws + FIXED;
    char*  eba   = ebq + (size_t)CB * EBQ;
    char*  qb    = eba + (size_t)CB * EBA;
    char*  qpb   = qb  + (size_t)CB * QB;
    char*  ab    = qpb + (size_t)CB * QB;
    float* rowP  = (float*)(ab + (size_t)CB * AB);
    float* colM  = rowP + (size_t)CB * 512;

    prep2_kernel<<<FP, 256, 0, stream>>>(conv_w, conv_b, U,
                                         (ushort16*)wt2, (ushort16*)wp2, bias2, bp2);

    for (int b0 = 0; b0 < Bb; b0 += CB) {
        int nb = (Bb - b0 < CB) ? (Bb - b0) : CB;
        gather_kernel<<<dim3(nb, 130), 128, 0, stream>>>(
            question + (size_t)b0 * QLn, QLn, emb, ebq, 130);
        gather_kernel<<<dim3(nb, 514), 128, 0, stream>>>(
            answer + (size_t)b0 * ALn, ALn, emb, eba, 514);

        int blocksQ = ((nb + 7) / 8) * 8 * 8;
        convq_mfma<<<blocksQ, 256, 0, stream>>>(ebq, wt2, wp2, bias2, bp2,
                                                (ushort16*)qb, (ushort16*)qpb, nb);
        int tilesA = nb * 4;
        int blocksA = ((tilesA + 7) / 8) * 8 * 4;
        conva_mfma<<<blocksA, 256, 0, stream>>>(eba, wt2, bias2, (ushort16*)ab, tilesA);

        int blocksG = ((nb + 7) / 8) * 8 * 4;
        fused_g<<<blocksG, 256, 0, stream>>>((const ushort16*)qpb, (const ushort16*)ab,
                                             rowP, colM, nb);
        fused_pool<<<nb, 256, 0, stream>>>((const ushort16*)qb, (const ushort16*)ab,
                                           rowP, colM, out + b0);
    }
}

// Round 5
// 925.257 us; speedup vs baseline: 13.2548x; 1.2351x over previous
//
#include <hip/hip_runtime.h>
#include <math.h>

typedef unsigned int   uint32;
typedef unsigned short ushort16;
typedef __attribute__((ext_vector_type(8))) short  short8;   // 8 bf16 (MFMA A/B frag)
typedef __attribute__((ext_vector_type(4))) float  floatx4;  // MFMA C/D frag

// Problem dims
#define Bb   512
#define QLn  128
#define ALn  512
#define En   300
#define Fn   400
#define FP   512      // f padded 400 -> 512 (zero weights/bias beyond 400)
#define EPAD 320      // e padded 300 -> 320 per shift; K_total = 3*320 = 960
#define NV   50001    // vocab rows incl. padding row 0

typedef const __attribute__((address_space(1))) unsigned int guint_t;
typedef __attribute__((address_space(3))) unsigned int luint_t;
// async global->LDS DMA, 16B/lane; global addr is per-lane, LDS dest = base + lane*16
#define GLDS16(g, l) __builtin_amdgcn_global_load_lds((guint_t*)(g), (luint_t*)(l), 16, 0, 0)

static __device__ __forceinline__ float bf_lo(uint32 u) { return __uint_as_float(u << 16); }
static __device__ __forceinline__ float bf_hi(uint32 u) { return __uint_as_float(u & 0xffff0000u); }
static __device__ __forceinline__ ushort16 f2bf(float f) {
    uint32 u = __float_as_uint(f);
    uint32 r = (u + 0x7fffu + ((u >> 16) & 1u)) >> 16;   // RNE
    return (ushort16)r;
}

// ---------------------------------------------------------------------------
// embcvt: embbf[v][0..320) = bf16(emb[v][0..300)), e>=300 zero. Row 0 stays 0.
// ---------------------------------------------------------------------------
__global__ __launch_bounds__(128) void embcvt_kernel(
        const float* __restrict__ emb, char* __restrict__ embbf)
{
    const int r = blockIdx.x, j = threadIdx.x;
    const float* er = emb + (size_t)r * En;
    uint32* orow = (uint32*)(embbf + (size_t)r * 640);
    for (int d = j; d < 160; d += 128) {
        uint32 v = 0;
        if (d < 150) {
            float2 f2v = *(const float2*)(er + 2 * d);
            v = (uint32)f2bf(f2v.x) | ((uint32)f2bf(f2v.y) << 16);
        }
        orow[d] = v;
    }
}

// ---------------------------------------------------------------------------
// prep2: Wt2[f][p] = W[f][e][kk] (p = kk*320+e) bf16, zero-padded f<512,e<320
//        Wp2[g][p] = sum_f U[f][g]*W[f][e][kk];  bias2[f]=cb[f]; bp2[g]=U^T cb
// ---------------------------------------------------------------------------
__global__ __launch_bounds__(256) void prep2_kernel(
        const float* __restrict__ W,   // [400][300][3]
        const float* __restrict__ cb,  // [400]
        const float* __restrict__ U,   // [400][400]
        ushort16* __restrict__ Wt2,    // [512][960] bf16
        ushort16* __restrict__ Wp2,    // [512][960] bf16
        float* __restrict__ bias2, float* __restrict__ bp2)
{
    const int g = blockIdx.x;
    const int t = threadIdx.x;
    __shared__ float Ucol[Fn];
    __shared__ float red[256];
    for (int f = t; f < Fn; f += 256) Ucol[f] = (g < Fn) ? U[f * Fn + g] : 0.f;
    __syncthreads();

    for (int p = t; p < 960; p += 256) {
        int kk = p / EPAD, e = p - kk * EPAD;
        float wv = 0.f, wpv = 0.f;
        if (e < En) {
            if (g < Fn) wv = W[(size_t)g * 900 + e * 3 + kk];
            for (int f = 0; f < Fn; ++f) wpv += Ucol[f] * W[(size_t)f * 900 + e * 3 + kk];
        }
        Wt2[(size_t)g * 960 + p] = f2bf(wv);
        Wp2[(size_t)g * 960 + p] = f2bf(wpv);
    }

    float part = 0.f;
    for (int f = t; f < Fn; f += 256) part += Ucol[f] * cb[f];
    red[t] = part; __syncthreads();
    for (int s = 128; s > 0; s >>= 1) { if (t < s) red[t] += red[t + s]; __syncthreads(); }
    if (t == 0) { bp2[g] = red[0]; bias2[g] = (g < Fn) ? cb[g] : 0.f; }
}

// ---------------------------------------------------------------------------
// conv tile body with in-staging gather: 128x128 out tile, K=960.
// A rows come straight from embbf[tok] via per-lane global_load_lds addresses;
// 6 row-base pointers (3 shifts x 2 row halves) precomputed per lane.
// XOR swizzle by source-chunk permutation (cg); LDS row stride 64 B.
// ---------------------------------------------------------------------------
static __device__ __forceinline__ void conv_tile_g(
        const int* __restrict__ tokrow,  // sequence base (chunk-local batch)
        int l0, int L,
        const char* __restrict__ embbf,
        const char* __restrict__ WB,     // weight z-slice, row stride 1920
        const float* __restrict__ biasv, int col0,
        ushort16* __restrict__ ob,       // out row base, row stride FP
        char* As, char* Bs)
{
    const int t = threadIdx.x, lane = t & 63, w = t >> 6;
    const int wr = w >> 1, wc = w & 1;
    const int fm = lane & 15;
    const int cg = ((lane & 3) - ((lane >> 3) & 3)) & 3;
    const int srow = w * 16 + (lane >> 2);
    const int chunkOff = (((lane >> 4) + (fm >> 1)) & 3) * 16;

    // per-lane gathered A source bases
    const char* srcA[3][2];
#pragma unroll
    for (int kk = 0; kk < 3; ++kk)
#pragma unroll
        for (int i = 0; i < 2; ++i) {
            const int pos = l0 + srow + i * 64 - 1 + kk;
            const int tok = (pos >= 0 && pos < L) ? tokrow[pos] : 0;
            srcA[kk][i] = embbf + (size_t)tok * 640 + cg * 16;
        }
    const char* srcB = WB + (size_t)srow * 1920 + cg * 16;
    char* AsW = As + w * 1024;
    char* BsW = Bs + w * 1024;

    floatx4 acc[4][4];
    const floatx4 zz = {0.f, 0.f, 0.f, 0.f};
#pragma unroll
    for (int m = 0; m < 4; ++m)
#pragma unroll
        for (int n = 0; n < 4; ++n) acc[m][n] = zz;

#pragma unroll
    for (int kk = 0; kk < 3; ++kk) {
        for (int ks = 0; ks < 10; ++ks) {
            const int ko = ks * 64;
            __syncthreads();
            GLDS16(srcA[kk][0] + ko,                 AsW);
            GLDS16(srcA[kk][1] + ko,                 AsW + 4096);
            GLDS16(srcB + kk * 640 + ko,             BsW);
            GLDS16(srcB + 122880 + kk * 640 + ko,    BsW + 4096);  // rows 64..127
            __syncthreads();

            short8 af[4], bf[4];
#pragma unroll
            for (int m = 0; m < 4; ++m)
                af[m] = *(const short8*)(As + (wr * 64 + m * 16 + fm) * 64 + chunkOff);
#pragma unroll
            for (int n = 0; n < 4; ++n)
                bf[n] = *(const short8*)(Bs + (wc * 64 + n * 16 + fm) * 64 + chunkOff);
#pragma unroll
            for (int m = 0; m < 4; ++m)
#pragma unroll
                for (int n = 0; n < 4; ++n)
                    acc[m][n] = __builtin_amdgcn_mfma_f32_16x16x32_bf16(
                        af[m], bf[n], acc[m][n], 0, 0, 0);
        }
    }

    float bn[4];
#pragma unroll
    for (int n = 0; n < 4; ++n) bn[n] = biasv[col0 + wc * 64 + n * 16 + fm];
#pragma unroll
    for (int m = 0; m < 4; ++m) {
        const int row = wr * 64 + m * 16 + ((lane >> 4) * 4);
#pragma unroll
        for (int n = 0; n < 4; ++n) {
            const int col = col0 + wc * 64 + n * 16 + fm;
#pragma unroll
            for (int r = 0; r < 4; ++r)
                ob[(size_t)(row + r) * FP + col] = f2bf(acc[m][n][r] + bn[n]);
        }
    }
}

// Merged conv dispatch. Region 1 (bx < blocksA): A-conv, tiles T=b*4+mt, 4 z.
// Region 2: Q-convs, tiles T=b, 8 z (z<4 -> Wt2->qb, else Wp2->qpb).
// XCD-affine: all z of a tile share an XCD (L2 reuse of gathered emb rows).
__global__ __launch_bounds__(256) void conv_all(
        const int* __restrict__ question, const int* __restrict__ answer,
        const char* __restrict__ embbf,
        const char* __restrict__ Wt2, const char* __restrict__ Wp2,
        const float* __restrict__ bias2, const float* __restrict__ bp2,
        ushort16* __restrict__ qb, ushort16* __restrict__ qpb,
        ushort16* __restrict__ ab, int nb, int blocksA)
{
    __shared__ __align__(16) char As[8192];
    __shared__ __align__(16) char Bs[8192];
    int bx = blockIdx.x;
    if (bx < blocksA) {
        const int xcd = bx & 7, rest = bx >> 3;
        const int z = rest & 3, g = rest >> 2;
        const int T = g * 8 + xcd;
        if (T >= nb * 4) return;
        const int b = T >> 2, mt = T & 3;
        conv_tile_g(answer + (size_t)b * ALn, mt * 128, ALn, embbf,
                    Wt2 + (size_t)z * 245760, bias2, z * 128,
                    ab + ((size_t)b * ALn + (size_t)mt * 128) * FP, As, Bs);
    } else {
        bx -= blocksA;
        const int xcd = bx & 7, rest = bx >> 3;
        const int z8 = rest & 7, g = rest >> 3;
        const int T = g * 8 + xcd;
        if (T >= nb) return;
        const int zf = z8 & 3;
        const char*  Wsel = (z8 < 4) ? Wt2 : Wp2;
        const float* bsel = (z8 < 4) ? bias2 : bp2;
        ushort16*    osel = (z8 < 4) ? qb : qpb;
        conv_tile_g(question + (size_t)T * QLn, 0, QLn, embbf,
                    Wsel + (size_t)zf * 245760, bsel, zf * 128,
                    osel + (size_t)T * QLn * FP, As, Bs);
    }
}

// ---------------------------------------------------------------------------
// fused_g: block (b, a-chunk c). Gpre = Q' A^T (K=416; cols 400..416 zeros).
// Emits per-chunk row maxes [nb][4][128] and col maxes [nb][512].
// ---------------------------------------------------------------------------
__global__ __launch_bounds__(256) void fused_g(
        const ushort16* __restrict__ Qp,   // [nb][128][512]
        const ushort16* __restrict__ Av,   // [nb][512][512]
        float* __restrict__ rowPart,       // [nb][4][128]
        float* __restrict__ colMg,         // [nb][512]
        int nb)
{
    __shared__ __align__(16) char Qs[8192];
    __shared__ __align__(16) char Asl[8192];
    __shared__ float rowM2[128][2];
    __shared__ float colM2[128][2];

    const int t = threadIdx.x, lane = t & 63, w = t >> 6;
    const int bx = blockIdx.x;
    const int xcd = bx & 7, rest = bx >> 3;
    const int c = rest & 3, g = rest >> 2;
    const int T = g * 8 + xcd;
    if (T >= nb) return;
    const int b = T;
    const int wr = w >> 1, wc = w & 1;
    const int fm = lane & 15;
    const int cg = ((lane & 3) - ((lane >> 3) & 3)) & 3;
    const int srow = w * 16 + (lane >> 2);
    const int chunkOff = (((lane >> 4) + (fm >> 1)) & 3) * 16;

    const char* Qpb = (const char*)Qp + (size_t)b * 131072;
    const char* Ab  = (const char*)Av + (size_t)b * 524288 + (size_t)c * 131072;
    const char* srcQ = Qpb + (size_t)srow * 1024 + cg * 16;
    const char* srcA = Ab  + (size_t)srow * 1024 + cg * 16;
    char* QsW = Qs + w * 1024;
    char* AsW = Asl + w * 1024;

    floatx4 acc[4][4];
    const floatx4 zz = {0.f, 0.f, 0.f, 0.f};
#pragma unroll
    for (int m = 0; m < 4; ++m)
#pragma unroll
        for (int n = 0; n < 4; ++n) acc[m][n] = zz;

    for (int ks = 0; ks < 13; ++ks) {
        const int colb = ks * 64;
        __syncthreads();
        GLDS16(srcQ + colb,         QsW);
        GLDS16(srcQ + 65536 + colb, QsW + 4096);
        GLDS16(srcA + colb,         AsW);
        GLDS16(srcA + 65536 + colb, AsW + 4096);
        __syncthreads();

        short8 qa[4], aa_[4];
#pragma unroll
        for (int m = 0; m < 4; ++m)
            qa[m] = *(const short8*)(Qs + (wr * 64 + m * 16 + fm) * 64 + chunkOff);
#pragma unroll
        for (int n = 0; n < 4; ++n)
            aa_[n] = *(const short8*)(Asl + (wc * 64 + n * 16 + fm) * 64 + chunkOff);
#pragma unroll
        for (int m = 0; m < 4; ++m)
#pragma unroll
            for (int n = 0; n < 4; ++n)
                acc[m][n] = __builtin_amdgcn_mfma_f32_16x16x32_bf16(
                    qa[m], aa_[n], acc[m][n], 0, 0, 0);
    }

    // row maxes (q rows): max over n-frags, xor-reduce over fm (cols)
#pragma unroll
    for (int m = 0; m < 4; ++m)
#pragma unroll
        for (int r = 0; r < 4; ++r) {
            float v = fmaxf(fmaxf(acc[m][0][r], acc[m][1][r]),
                            fmaxf(acc[m][2][r], acc[m][3][r]));
            v = fmaxf(v, __shfl_xor(v, 1));
            v = fmaxf(v, __shfl_xor(v, 2));
            v = fmaxf(v, __shfl_xor(v, 4));
            v = fmaxf(v, __shfl_xor(v, 8));
            if (fm == 0) rowM2[wr * 64 + m * 16 + (lane >> 4) * 4 + r][wc] = v;
        }
    // col maxes: max over (m, reg), xor-reduce over row quads
#pragma unroll
    for (int n = 0; n < 4; ++n) {
        float v = -1e30f;
#pragma unroll
        for (int m = 0; m < 4; ++m)
#pragma unroll
            for (int r = 0; r < 4; ++r) v = fmaxf(v, acc[m][n][r]);
        v = fmaxf(v, __shfl_xor(v, 16));
        v = fmaxf(v, __shfl_xor(v, 32));
        if (lane < 16) colM2[wc * 64 + n * 16 + lane][wr] = v;
    }
    __syncthreads();
    if (t < 128) {
        rowPart[((size_t)b * 4 + c) * 128 + t] = fmaxf(rowM2[t][0], rowM2[t][1]);
        colMg[(size_t)b * 512 + c * 128 + t]   = fmaxf(colM2[t][0], colM2[t][1]);
    }
}

// ---------------------------------------------------------------------------
// fused_pool: per-batch softmax over tanh(maxes) + pooling + cosine.
// ---------------------------------------------------------------------------
static __device__ __forceinline__ float block_reduce_max(float v, volatile float* red) {
    int t = threadIdx.x;
    red[t] = v; __syncthreads();
    for (int s = 128; s > 0; s >>= 1) {
        if (t < s) red[t] = fmaxf(red[t], red[t + s]);
        __syncthreads();
    }
    float r = red[0]; __syncthreads();
    return r;
}
static __device__ __forceinline__ float block_reduce_sum(float v, volatile float* red) {
    int t = threadIdx.x;
    red[t] = v; __syncthreads();
    for (int s = 128; s > 0; s >>= 1) {
        if (t < s) red[t] = red[t] + red[t + s];
        __syncthreads();
    }
    float r = red[0]; __syncthreads();
    return r;
}

__global__ __launch_bounds__(256) void fused_pool(
        const ushort16* __restrict__ Qv,   // [nb][128][512]
        const ushort16* __restrict__ Av,   // [nb][512][512]
        const float* __restrict__ rowPart, // [nb][4][128]
        const float* __restrict__ colMg,   // [nb][512]
        float* __restrict__ out)
{
    __shared__ float colv[ALn];
    __shared__ float roq[QLn];
    __shared__ float red[256];
    const int t = threadIdx.x, b = blockIdx.x;

    float v = -1e30f;
    if (t < QLn) {
        const float* rp = rowPart + (size_t)b * 512;
        float rm = fmaxf(fmaxf(rp[t], rp[128 + t]), fmaxf(rp[256 + t], rp[384 + t]));
        v = tanhf(rm);
    }
    float vmax = block_reduce_max(v, red);
    float ex = (t < QLn) ? __expf(v - vmax) : 0.f;
    float ssum = block_reduce_sum(ex, red);
    if (t < QLn) roq[t] = ex / ssum;

    float c0 = tanhf(colMg[(size_t)b * 512 + t]);
    float c1 = tanhf(colMg[(size_t)b * 512 + 256 + t]);
    float cmax = block_reduce_max(fmaxf(c0, c1), red);
    float e0 = __expf(c0 - cmax), e1 = __expf(c1 - cmax);
    float csum = block_reduce_sum(e0 + e1, red);
    colv[t] = e0 / csum;
    colv[t + 256] = e1 / csum;
    __syncthreads();

    const uint32* Qb32 = (const uint32*)((const char*)Qv + (size_t)b * 131072);
    float rq0 = 0.f, rq1 = 0.f;
#pragma unroll 4
    for (int q = 0; q < QLn; ++q) {
        float wv = roq[q];
        uint32 u = Qb32[q * 256 + t];
        rq0 = fmaf(bf_lo(u), wv, rq0);
        rq1 = fmaf(bf_hi(u), wv, rq1);
    }
    const uint32* Ab32 = (const uint32*)((const char*)Av + (size_t)b * 524288);
    float ra0 = 0.f, ra1 = 0.f;
#pragma unroll 4
    for (int a = 0; a < ALn; ++a) {
        float wv = colv[a];
        uint32 u = Ab32[a * 256 + t];
        ra0 = fmaf(bf_lo(u), wv, ra0);
        ra1 = fmaf(bf_hi(u), wv, ra1);
    }

    float dd  = block_reduce_sum(rq0 * ra0 + rq1 * ra1, red);
    float qq  = block_reduce_sum(rq0 * rq0 + rq1 * rq1, red);
    float aam = block_reduce_sum(ra0 * ra0 + ra1 * ra1, red);
    if (t == 0) {
        float nq = fmaxf(sqrtf(qq), 1e-8f);
        float na = fmaxf(sqrtf(aam), 1e-8f);
        out[b] = dd / (nq * na);
    }
}

// ---------------------------------------------------------------------------
// launch — ws_size-adaptive batch chunking (pure function of ws_size).
// ws: [Wt2 | Wp2 | bias2/bp2 | embbf(32MB) | per-chunk: qb qpb ab rowP colM]
// ---------------------------------------------------------------------------
extern "C" void kernel_launch(void* const* d_in, const int* in_sizes, int n_in,
                              void* d_out, int out_size, void* d_ws, size_t ws_size,
                              hipStream_t stream)
{
    const int*   question = (const int*)d_in[0];
    const int*   answer   = (const int*)d_in[1];
    const float* emb      = (const float*)d_in[2];
    const float* conv_w   = (const float*)d_in[3];
    const float* conv_b   = (const float*)d_in[4];
    const float* U        = (const float*)d_in[5];
    float* out = (float*)d_out;
    char* ws = (char*)d_ws;

    const size_t WT2B   = (size_t)FP * 960 * 2;          // 983,040
    const size_t EMBB   = (size_t)NV * 640;              // 32,000,640
    const size_t FIXED0 = 2 * WT2B + 4096;               // 1,970,176
    const size_t FIXED  = FIXED0 + EMBB;                 // 33,970,816
    const size_t QB     = (size_t)QLn * FP * 2;          // 131,072
    const size_t AB     = (size_t)ALn * FP * 2;          // 524,288
    const size_t MXB    = 4096;                          // rowPart + colMg
    const size_t PER_B  = 2 * QB + AB + MXB;             // 790,528

    size_t avail = (ws_size > FIXED) ? (ws_size - FIXED) : 0;
    int CB = (int)(avail / PER_B);
    if (CB > Bb) CB = Bb;
    if (CB < 1)  CB = 1;

    char*  wt2   = ws;
    char*  wp2   = ws + WT2B;
    float* bias2 = (float*)(ws + 2 * WT2B);
    float* bp2   = (float*)(ws + 2 * WT2B + 2048);
    char*  embbf = ws + FIXED0;
    char*  qb    = ws + FIXED;
    char*  qpb   = qb  + (size_t)CB * QB;
    char*  ab    = qpb + (size_t)CB * QB;
    float* rowP  = (float*)(ab + (size_t)CB * AB);
    float* colM  = rowP + (size_t)CB * 512;

    embcvt_kernel<<<NV, 128, 0, stream>>>(emb, embbf);
    prep2_kernel<<<FP, 256, 0, stream>>>(conv_w, conv_b, U,
                                         (ushort16*)wt2, (ushort16*)wp2, bias2, bp2);

    for (int b0 = 0; b0 < Bb; b0 += CB) {
        int nb = (Bb - b0 < CB) ? (Bb - b0) : CB;
        int blocksA = ((nb * 4 + 7) / 8) * 8 * 4;
        int blocksQ = ((nb + 7) / 8) * 8 * 8;
        conv_all<<<blocksA + blocksQ, 256, 0, stream>>>(
            question + (size_t)b0 * QLn, answer + (size_t)b0 * ALn, embbf,
            wt2, wp2, bias2, bp2,
            (ushort16*)qb, (ushort16*)qpb, (ushort16*)ab, nb, blocksA);

        int blocksG = ((nb + 7) / 8) * 8 * 4;
        fused_g<<<blocksG, 256, 0, stream>>>((const ushort16*)qpb, (const ushort16*)ab,
                                             rowP, colM, nb);
        fused_pool<<<nb, 256, 0, stream>>>((const ushort16*)qb, (const ushort16*)ab,
                                           rowP, colM, out + b0);
    }
}

// Round 6
// 799.280 us; speedup vs baseline: 15.3440x; 1.1576x over previous
//
#include <hip/hip_runtime.h>
#include <math.h>

typedef unsigned int   uint32;
typedef unsigned short ushort16;
typedef __attribute__((ext_vector_type(8))) short  short8;   // 8 bf16 (MFMA A/B frag)
typedef __attribute__((ext_vector_type(4))) float  floatx4;  // MFMA C/D frag

// Problem dims
#define Bb   512
#define QLn  128
#define ALn  512
#define En   300
#define Fn   400
#define OW   416      // packed output width: 400 real + 16 zero (832 B = 13*64)
#define EPAD 320      // e padded 300 -> 320 per shift; K_total = 3*320 = 960
#define NV   50001

typedef const __attribute__((address_space(1))) unsigned int guint_t;
typedef __attribute__((address_space(3))) unsigned int luint_t;
#define GLDS16(g, l) __builtin_amdgcn_global_load_lds((guint_t*)(g), (luint_t*)(l), 16, 0, 0)

static __device__ __forceinline__ float bf_lo(uint32 u) { return __uint_as_float(u << 16); }
static __device__ __forceinline__ float bf_hi(uint32 u) { return __uint_as_float(u & 0xffff0000u); }
static __device__ __forceinline__ ushort16 f2bf(float f) {
    uint32 u = __float_as_uint(f);
    uint32 r = (u + 0x7fffu + ((u >> 16) & 1u)) >> 16;   // RNE
    return (ushort16)r;
}
static __device__ __forceinline__ uint32 pack2(float a, float b) {
    return (uint32)f2bf(a) | ((uint32)f2bf(b) << 16);
}

// ---------------------------------------------------------------------------
// embcvt: embbf[v][0..320) = bf16(emb[v][0..300)), e>=300 zero.
// ---------------------------------------------------------------------------
__global__ __launch_bounds__(128) void embcvt_kernel(
        const float* __restrict__ emb, char* __restrict__ embbf)
{
    const int r = blockIdx.x, j = threadIdx.x;
    const float* er = emb + (size_t)r * En;
    uint32* orow = (uint32*)(embbf + (size_t)r * 640);
    for (int d = j; d < 160; d += 128) {
        uint32 v = 0;
        if (d < 150) {
            float2 f2v = *(const float2*)(er + 2 * d);
            v = pack2(f2v.x, f2v.y);
        }
        orow[d] = v;
    }
}

// ---------------------------------------------------------------------------
// prep_wt: Wt2[f][p] = W[f][e*3+kk] (p = kk*320+e), bf16, zero pad; bias2.
// ---------------------------------------------------------------------------
__global__ __launch_bounds__(256) void prep_wt(
        const float* __restrict__ W, const float* __restrict__ cb,
        ushort16* __restrict__ Wt2, float* __restrict__ bias2)
{
    const int f = blockIdx.x, t = threadIdx.x;
    for (int p2 = t; p2 < 480; p2 += 256) {
        int p = 2 * p2;
        float v0 = 0.f, v1 = 0.f;
        if (f < Fn) {
            int kk = p / EPAD, e = p - kk * EPAD;
            if (e < En)     v0 = W[(size_t)f * 900 + e * 3 + kk];
            if (e + 1 < En) v1 = W[(size_t)f * 900 + (e + 1) * 3 + kk];
        }
        *(uint32*)&Wt2[(size_t)f * 960 + p] = pack2(v0, v1);
    }
    if (t == 0) bias2[f] = (f < Fn) ? cb[f] : 0.f;
}

// ---------------------------------------------------------------------------
// prep_wp: Wp2[g][p] = sum_f U[f][g]*W[f][p900], fp32 accum, bf16 store.
// grid (30 p-chunks of 32, 4 g-chunks of 128). W chunk staged in LDS.
// ---------------------------------------------------------------------------
__global__ __launch_bounds__(256) void prep_wp(
        const float* __restrict__ W, const float* __restrict__ U,
        ushort16* __restrict__ Wp2)
{
    __shared__ float Wl[400 * 32];   // 51.2 KB
    const int t = threadIdx.x;
    const int pc = blockIdx.x, gc = blockIdx.y;
    const int kk = (pc * 32) / EPAD, e0 = pc * 32 - kk * EPAD;

    for (int i = t; i < 400 * 32; i += 256) {
        int f = i >> 5, j = i & 31, e = e0 + j;
        Wl[i] = (e < En) ? W[(size_t)f * 900 + e * 3 + kk] : 0.f;
    }
    __syncthreads();

    const int g = gc * 128 + (t >> 1);
    const int jh = (t & 1) * 16;
    float acc[16];
#pragma unroll
    for (int k = 0; k < 16; ++k) acc[k] = 0.f;

    for (int f = 0; f < Fn; ++f) {
        float uf = 0.f;
        if (g < Fn) uf = U[(size_t)f * Fn + g];
        const float* wl = Wl + f * 32 + jh;
#pragma unroll
        for (int k = 0; k < 16; ++k) acc[k] = fmaf(uf, wl[k], acc[k]);
    }
    ushort16* orow = Wp2 + (size_t)g * 960 + pc * 32 + jh;
#pragma unroll
    for (int k = 0; k < 16; k += 2)
        *(uint32*)&orow[k] = pack2(acc[k], acc[k + 1]);
}

// prep_bp: bp2[g] = sum_f U[f][g]*cb[f] (g<512, zero beyond 400)
__global__ __launch_bounds__(256) void prep_bp(
        const float* __restrict__ cb, const float* __restrict__ U,
        float* __restrict__ bp2)
{
    __shared__ float cbl[Fn];
    const int t = threadIdx.x;
    for (int f = t; f < Fn; f += 256) cbl[f] = cb[f];
    __syncthreads();
#pragma unroll
    for (int h = 0; h < 2; ++h) {
        int g = t + h * 256;
        float s = 0.f;
        if (g < Fn)
            for (int f = 0; f < Fn; ++f) s += cbl[f] * U[(size_t)f * Fn + g];
        bp2[g] = s;
    }
}

// ---------------------------------------------------------------------------
// conv tile body (templated on NF = n-frags per wave-col).
// NF=4: 128-col tile. NF=5: 144-col tile (cols col0..col0+144), wc0/wc1
// overlap 16 cols; wc0 stores frags 0..3, wc1 stores 0..4 + zero-pad 400..416.
// A rows gathered from embbf[tok] via per-lane GLDS; XOR swizzle by source-
// chunk permutation (16-row-aligned groups keep the slot invariant).
// ---------------------------------------------------------------------------
template<int NF>
static __device__ __forceinline__ void conv_tile_g(
        const int* __restrict__ tokrow, int l0, int L,
        const char* __restrict__ embbf,
        const char* __restrict__ WB,     // weight base already offset to col0
        const float* __restrict__ biasv, int col0,
        ushort16* __restrict__ ob,       // out row base, row stride OW
        char* As, char* Bs)
{
    const int t = threadIdx.x, lane = t & 63, w = t >> 6;
    const int wr = w >> 1, wc = w & 1;
    const int fm = lane & 15;
    const int cg = ((lane & 3) - ((lane >> 3) & 3)) & 3;
    const int srow = w * 16 + (lane >> 2);
    const int chunkOff = (((lane >> 4) + (fm >> 1)) & 3) * 16;

    const char* srcA[3][2];
#pragma unroll
    for (int kk = 0; kk < 3; ++kk)
#pragma unroll
        for (int i = 0; i < 2; ++i) {
            const int pos = l0 + srow + i * 64 - 1 + kk;
            const int tok = (pos >= 0 && pos < L) ? tokrow[pos] : 0;
            srcA[kk][i] = embbf + (size_t)tok * 640 + cg * 16;
        }
    const char* srcB0 = WB + (size_t)srow * 1920 + cg * 16;
    const char* srcB8 = WB + (size_t)(128 + (lane >> 2)) * 1920 + cg * 16;
    char* AsW = As + w * 1024;
    char* BsW = Bs + w * 1024;

    floatx4 acc[4][NF];
    const floatx4 zz = {0.f, 0.f, 0.f, 0.f};
#pragma unroll
    for (int m = 0; m < 4; ++m)
#pragma unroll
        for (int n = 0; n < NF; ++n) acc[m][n] = zz;

#pragma unroll
    for (int kk = 0; kk < 3; ++kk) {
        for (int ks = 0; ks < 10; ++ks) {
            const int ko = ks * 64;
            const int wo = kk * 640 + ko;
            __syncthreads();
            GLDS16(srcA[kk][0] + ko,     AsW);
            GLDS16(srcA[kk][1] + ko,     AsW + 4096);
            GLDS16(srcB0 + wo,           BsW);
            GLDS16(srcB0 + 122880 + wo,  BsW + 4096);
            if (NF == 5 && w == 0) GLDS16(srcB8 + wo, Bs + 8192);
            __syncthreads();

            short8 af[4], bf[NF];
#pragma unroll
            for (int m = 0; m < 4; ++m)
                af[m] = *(const short8*)(As + (wr * 64 + m * 16 + fm) * 64 + chunkOff);
#pragma unroll
            for (int n = 0; n < NF; ++n)
                bf[n] = *(const short8*)(Bs + (wc * 64 + n * 16 + fm) * 64 + chunkOff);
#pragma unroll
            for (int m = 0; m < 4; ++m)
#pragma unroll
                for (int n = 0; n < NF; ++n)
                    acc[m][n] = __builtin_amdgcn_mfma_f32_16x16x32_bf16(
                        af[m], bf[n], acc[m][n], 0, 0, 0);
        }
    }

    float bn[NF];
#pragma unroll
    for (int n = 0; n < NF; ++n) bn[n] = biasv[col0 + wc * 64 + n * 16 + fm];
    const int nStore = (NF == 5 && wc == 0) ? 4 : NF;
#pragma unroll
    for (int m = 0; m < 4; ++m) {
        const int row = wr * 64 + m * 16 + ((lane >> 4) * 4);
#pragma unroll
        for (int n = 0; n < NF; ++n) {
            if (n >= nStore) break;
            const int col = col0 + wc * 64 + n * 16 + fm;
#pragma unroll
            for (int r = 0; r < 4; ++r)
                ob[(size_t)(row + r) * OW + col] = f2bf(acc[m][n][r] + bn[n]);
        }
        if (NF == 5 && wc == 1) {
#pragma unroll
            for (int r = 0; r < 4; ++r)
                ob[(size_t)(row + r) * OW + 400 + fm] = (ushort16)0;
        }
    }
}

// Merged conv dispatch. Region 1 (bx < blocksA): A-conv, tiles T=b*4+mt, 3 z.
// Region 2: Q-convs, tiles T=b, 6 (z,wsel) variants. XCD-affine tile placement.
__global__ __launch_bounds__(256) void conv_all(
        const int* __restrict__ question, const int* __restrict__ answer,
        const char* __restrict__ embbf,
        const char* __restrict__ Wt2, const char* __restrict__ Wp2,
        const float* __restrict__ bias2, const float* __restrict__ bp2,
        ushort16* __restrict__ qb, ushort16* __restrict__ qpb,
        ushort16* __restrict__ ab, int nb, int blocksA)
{
    __shared__ __align__(16) char As[8192];
    __shared__ __align__(16) char Bs[9216];
    int bx = blockIdx.x;
    if (bx < blocksA) {
        const int xcd = bx & 7, rest = bx >> 3;
        const int z = rest % 3, g = rest / 3;
        const int T = g * 8 + xcd;
        if (T >= nb * 4) return;
        const int b = T >> 2, mt = T & 3;
        ushort16* ob = ab + ((size_t)b * ALn + (size_t)mt * 128) * OW;
        const int* tr = answer + (size_t)b * ALn;
        if (z == 2)
            conv_tile_g<5>(tr, mt * 128, ALn, embbf, Wt2 + (size_t)256 * 1920,
                           bias2, 256, ob, As, Bs);
        else
            conv_tile_g<4>(tr, mt * 128, ALn, embbf, Wt2 + (size_t)z * 245760,
                           bias2, z * 128, ob, As, Bs);
    } else {
        bx -= blocksA;
        const int xcd = bx & 7, rest = bx >> 3;
        const int z6 = rest % 6, g = rest / 6;
        const int T = g * 8 + xcd;
        if (T >= nb) return;
        const int zf = z6 >> 1, ws = z6 & 1;
        const char*  Wsel = ws ? Wp2 : Wt2;
        const float* bsel = ws ? bp2 : bias2;
        ushort16*    ob   = (ws ? qpb : qb) + (size_t)T * QLn * OW;
        const int* tr = question + (size_t)T * QLn;
        if (zf == 2)
            conv_tile_g<5>(tr, 0, QLn, embbf, Wsel + (size_t)256 * 1920,
                           bsel, 256, ob, As, Bs);
        else
            conv_tile_g<4>(tr, 0, QLn, embbf, Wsel + (size_t)zf * 245760,
                           bsel, zf * 128, ob, As, Bs);
    }
}

// ---------------------------------------------------------------------------
// fused_g: block (b, a-chunk c). Gpre = Q' A^T (K=416, cols 400..416 zeros).
// ---------------------------------------------------------------------------
__global__ __launch_bounds__(256) void fused_g(
        const ushort16* __restrict__ Qp,   // [nb][128][416]
        const ushort16* __restrict__ Av,   // [nb][512][416]
        float* __restrict__ rowPart,       // [nb][4][128]
        float* __restrict__ colMg,         // [nb][512]
        int nb)
{
    __shared__ __align__(16) char Qs[8192];
    __shared__ __align__(16) char Asl[8192];
    __shared__ float rowM2[128][2];
    __shared__ float colM2[128][2];

    const int t = threadIdx.x, lane = t & 63, w = t >> 6;
    const int bx = blockIdx.x;
    const int xcd = bx & 7, rest = bx >> 3;
    const int c = rest & 3, g = rest >> 2;
    const int T = g * 8 + xcd;
    if (T >= nb) return;
    const int b = T;
    const int wr = w >> 1, wc = w & 1;
    const int fm = lane & 15;
    const int cg = ((lane & 3) - ((lane >> 3) & 3)) & 3;
    const int srow = w * 16 + (lane >> 2);
    const int chunkOff = (((lane >> 4) + (fm >> 1)) & 3) * 16;

    const char* Qpb = (const char*)Qp + (size_t)b * 106496;
    const char* Ab  = (const char*)Av + (size_t)b * 425984 + (size_t)c * 106496;
    const char* srcQ = Qpb + (size_t)srow * 832 + cg * 16;
    const char* srcA = Ab  + (size_t)srow * 832 + cg * 16;
    char* QsW = Qs + w * 1024;
    char* AsW = Asl + w * 1024;

    floatx4 acc[4][4];
    const floatx4 zz = {0.f, 0.f, 0.f, 0.f};
#pragma unroll
    for (int m = 0; m < 4; ++m)
#pragma unroll
        for (int n = 0; n < 4; ++n) acc[m][n] = zz;

    for (int ks = 0; ks < 13; ++ks) {
        const int colb = ks * 64;
        __syncthreads();
        GLDS16(srcQ + colb,         QsW);
        GLDS16(srcQ + 53248 + colb, QsW + 4096);
        GLDS16(srcA + colb,         AsW);
        GLDS16(srcA + 53248 + colb, AsW + 4096);
        __syncthreads();

        short8 qa[4], aa_[4];
#pragma unroll
        for (int m = 0; m < 4; ++m)
            qa[m] = *(const short8*)(Qs + (wr * 64 + m * 16 + fm) * 64 + chunkOff);
#pragma unroll
        for (int n = 0; n < 4; ++n)
            aa_[n] = *(const short8*)(Asl + (wc * 64 + n * 16 + fm) * 64 + chunkOff);
#pragma unroll
        for (int m = 0; m < 4; ++m)
#pragma unroll
            for (int n = 0; n < 4; ++n)
                acc[m][n] = __builtin_amdgcn_mfma_f32_16x16x32_bf16(
                    qa[m], aa_[n], acc[m][n], 0, 0, 0);
    }

#pragma unroll
    for (int m = 0; m < 4; ++m)
#pragma unroll
        for (int r = 0; r < 4; ++r) {
            float v = fmaxf(fmaxf(acc[m][0][r], acc[m][1][r]),
                            fmaxf(acc[m][2][r], acc[m][3][r]));
            v = fmaxf(v, __shfl_xor(v, 1));
            v = fmaxf(v, __shfl_xor(v, 2));
            v = fmaxf(v, __shfl_xor(v, 4));
            v = fmaxf(v, __shfl_xor(v, 8));
            if (fm == 0) rowM2[wr * 64 + m * 16 + (lane >> 4) * 4 + r][wc] = v;
        }
#pragma unroll
    for (int n = 0; n < 4; ++n) {
        float v = -1e30f;
#pragma unroll
        for (int m = 0; m < 4; ++m)
#pragma unroll
            for (int r = 0; r < 4; ++r) v = fmaxf(v, acc[m][n][r]);
        v = fmaxf(v, __shfl_xor(v, 16));
        v = fmaxf(v, __shfl_xor(v, 32));
        if (lane < 16) colM2[wc * 64 + n * 16 + lane][wr] = v;
    }
    __syncthreads();
    if (t < 128) {
        rowPart[((size_t)b * 4 + c) * 128 + t] = fmaxf(rowM2[t][0], rowM2[t][1]);
        colMg[(size_t)b * 512 + c * 128 + t]   = fmaxf(colM2[t][0], colM2[t][1]);
    }
}

// ---------------------------------------------------------------------------
// fused_pool: per-batch softmax over tanh(maxes) + pooling + cosine.
// ---------------------------------------------------------------------------
static __device__ __forceinline__ float block_reduce_max(float v, volatile float* red) {
    int t = threadIdx.x;
    red[t] = v; __syncthreads();
    for (int s = 128; s > 0; s >>= 1) {
        if (t < s) red[t] = fmaxf(red[t], red[t + s]);
        __syncthreads();
    }
    float r = red[0]; __syncthreads();
    return r;
}
static __device__ __forceinline__ float block_reduce_sum(float v, volatile float* red) {
    int t = threadIdx.x;
    red[t] = v; __syncthreads();
    for (int s = 128; s > 0; s >>= 1) {
        if (t < s) red[t] = red[t] + red[t + s];
        __syncthreads();
    }
    float r = red[0]; __syncthreads();
    return r;
}

__global__ __launch_bounds__(256) void fused_pool(
        const ushort16* __restrict__ Qv,   // [nb][128][416]
        const ushort16* __restrict__ Av,   // [nb][512][416]
        const float* __restrict__ rowPart, // [nb][4][128]
        const float* __restrict__ colMg,   // [nb][512]
        float* __restrict__ out)
{
    __shared__ float colv[ALn];
    __shared__ float roq[QLn];
    __shared__ float red[256];
    const int t = threadIdx.x, b = blockIdx.x;

    float v = -1e30f;
    if (t < QLn) {
        const float* rp = rowPart + (size_t)b * 512;
        float rm = fmaxf(fmaxf(rp[t], rp[128 + t]), fmaxf(rp[256 + t], rp[384 + t]));
        v = tanhf(rm);
    }
    float vmax = block_reduce_max(v, red);
    float ex = (t < QLn) ? __expf(v - vmax) : 0.f;
    float ssum = block_reduce_sum(ex, red);
    if (t < QLn) roq[t] = ex / ssum;

    float c0 = tanhf(colMg[(size_t)b * 512 + t]);
    float c1 = tanhf(colMg[(size_t)b * 512 + 256 + t]);
    float cmax = block_reduce_max(fmaxf(c0, c1), red);
    float e0 = __expf(c0 - cmax), e1 = __expf(c1 - cmax);
    float csum = block_reduce_sum(e0 + e1, red);
    colv[t] = e0 / csum;
    colv[t + 256] = e1 / csum;
    __syncthreads();

    float rq0 = 0.f, rq1 = 0.f, ra0 = 0.f, ra1 = 0.f;
    if (t < 208) {
        const uint32* Qb32 = (const uint32*)((const char*)Qv + (size_t)b * 106496);
#pragma unroll 4
        for (int q = 0; q < QLn; ++q) {
            float wv = roq[q];
            uint32 u = Qb32[q * 208 + t];
            rq0 = fmaf(bf_lo(u), wv, rq0);
            rq1 = fmaf(bf_hi(u), wv, rq1);
        }
        const uint32* Ab32 = (const uint32*)((const char*)Av + (size_t)b * 425984);
#pragma unroll 4
        for (int a = 0; a < ALn; ++a) {
            float wv = colv[a];
            uint32 u = Ab32[a * 208 + t];
            ra0 = fmaf(bf_lo(u), wv, ra0);
            ra1 = fmaf(bf_hi(u), wv, ra1);
        }
    }

    float dd  = block_reduce_sum(rq0 * ra0 + rq1 * ra1, red);
    float qq  = block_reduce_sum(rq0 * rq0 + rq1 * rq1, red);
    float aam = block_reduce_sum(ra0 * ra0 + ra1 * ra1, red);
    if (t == 0) {
        float nq = fmaxf(sqrtf(qq), 1e-8f);
        float na = fmaxf(sqrtf(aam), 1e-8f);
        out[b] = dd / (nq * na);
    }
}

// ---------------------------------------------------------------------------
// launch — ws_size-adaptive balanced batch chunking (pure function of ws_size)
// ws: [Wt2 | Wp2 | bias2 | bp2 | embbf | per-chunk: qb qpb ab rowP colM]
// ---------------------------------------------------------------------------
extern "C" void kernel_launch(void* const* d_in, const int* in_sizes, int n_in,
                              void* d_out, int out_size, void* d_ws, size_t ws_size,
                              hipStream_t stream)
{
    const int*   question = (const int*)d_in[0];
    const int*   answer   = (const int*)d_in[1];
    const float* emb      = (const float*)d_in[2];
    const float* conv_w   = (const float*)d_in[3];
    const float* conv_b   = (const float*)d_in[4];
    const float* U        = (const float*)d_in[5];
    float* out = (float*)d_out;
    char* ws = (char*)d_ws;

    const size_t WT2B   = (size_t)512 * 960 * 2;         // 983,040
    const size_t EMBB   = (size_t)NV * 640;              // 32,000,640
    const size_t FIXED0 = 2 * WT2B + 4096;               // 1,970,176
    const size_t FIXED  = FIXED0 + EMBB;                 // 33,970,816
    const size_t QB     = (size_t)QLn * OW * 2;          // 106,496
    const size_t AB     = (size_t)ALn * OW * 2;          // 425,984
    const size_t MXB    = 4096;
    const size_t PER_B  = 2 * QB + AB + MXB;             // 643,072

    size_t avail = (ws_size > FIXED) ? (ws_size - FIXED) : 0;
    int CB = (int)(avail / PER_B);
    if (CB > Bb) CB = Bb;
    if (CB < 1)  CB = 1;
    int nch = (Bb + CB - 1) / CB;
    int CBe = (Bb + nch - 1) / nch;      // balanced chunk size (<= CB)

    char*  wt2   = ws;
    char*  wp2   = ws + WT2B;
    float* bias2 = (float*)(ws + 2 * WT2B);
    float* bp2   = (float*)(ws + 2 * WT2B + 2048);
    char*  embbf = ws + FIXED0;
    char*  qb    = ws + FIXED;
    char*  qpb   = qb  + (size_t)CB * QB;
    char*  ab    = qpb + (size_t)CB * QB;
    float* rowP  = (float*)(ab + (size_t)CB * AB);
    float* colM  = rowP + (size_t)CB * 512;

    embcvt_kernel<<<NV, 128, 0, stream>>>(emb, embbf);
    prep_wt<<<512, 256, 0, stream>>>(conv_w, conv_b, (ushort16*)wt2, bias2);
    prep_wp<<<dim3(30, 4), 256, 0, stream>>>(conv_w, U, (ushort16*)wp2);
    prep_bp<<<1, 256, 0, stream>>>(conv_b, U, bp2);

    for (int b0 = 0; b0 < Bb; b0 += CBe) {
        int nb = (Bb - b0 < CBe) ? (Bb - b0) : CBe;
        int blocksA = ((nb * 4 + 7) / 8) * 8 * 3;
        int blocksQ = ((nb + 7) / 8) * 8 * 6;
        conv_all<<<blocksA + blocksQ, 256, 0, stream>>>(
            question + (size_t)b0 * QLn, answer + (size_t)b0 * ALn, embbf,
            wt2, wp2, bias2, bp2,
            (ushort16*)qb, (ushort16*)qpb, (ushort16*)ab, nb, blocksA);

        int blocksG = ((nb + 7) / 8) * 8 * 4;
        fused_g<<<blocksG, 256, 0, stream>>>((const ushort16*)qpb, (const ushort16*)ab,
                                             rowP, colM, nb);
        fused_pool<<<nb, 256, 0, stream>>>((const ushort16*)qb, (const ushort16*)ab,
                                           rowP, colM, out + b0);
    }
}